// Round 9
// baseline (519.089 us; speedup 1.0000x reference)
//
#include <hip/hip_runtime.h>
#include <hip/hip_cooperative_groups.h>

namespace cg = cooperative_groups;

#define NB   32      // graphs
#define NPER 512     // nodes per graph
#define NN   16384   // total nodes
#define EE   262144  // edges
#define DD   128     // D_IN == D_OUT
#define AS   2048    // total clusters
#define KC   64      // clusters per graph
#define GRID 256     // cooperative grid: 1 block/CU — always co-resident

using short8   = __attribute__((ext_vector_type(8))) short;   // 8 bf16 (4 VGPRs)
using floatx4  = __attribute__((ext_vector_type(4))) float;   // MFMA acc
using ushort4v = __attribute__((ext_vector_type(4))) unsigned short;

typedef __attribute__((address_space(3))) unsigned int lds_u32;
typedef const __attribute__((address_space(1))) unsigned int gbl_u32;

// async 16B global -> LDS (wave-uniform base + lane*16; keep dest linear in tid)
static __device__ __forceinline__ void gload16(const unsigned short* g, unsigned short* l) {
    __builtin_amdgcn_global_load_lds((gbl_u32*)g, (lds_u32*)l, 16, 0, 0);
}

static __device__ __forceinline__ float bits2f(unsigned int u) {
    union { unsigned int i; float f; } z; z.i = u << 16; return z.f;
}
// float -> bf16 bits, round-to-nearest-even
static __device__ __forceinline__ unsigned short f2b(float x) {
    union { float f; unsigned int u; } v; v.f = x;
    unsigned int r = v.u + 0x7fffu + ((v.u >> 16) & 1u);
    return (unsigned short)(r >> 16);
}

// 64 KB LDS overlay shared by all phases
union __align__(16) SMem {
    unsigned short big[32768];  // 64KB: agg_h A-tile / as_mfma sT-tile
    struct { unsigned short lA[16384]; float raw[4352]; float ssq[256]; float rn[64]; } pool;
    struct { unsigned short lA[4096]; unsigned short lB[4096]; float red[256];
             unsigned short fT[17408]; } feat;
    struct { unsigned short lS[8192]; unsigned short lF[16384]; unsigned short lAS[8192]; } ha;
    struct { unsigned short fT[17408]; } prep;
    struct { float tl[32][33]; } tr;
};

__global__ __launch_bounds__(256, 1) void mega_kernel(
    const float* __restrict__ h, const float* __restrict__ Wf, const float* __restrict__ bfe,
    const float* __restrict__ Wp, const float* __restrict__ bp,
    const int* __restrict__ esrc, const int* __restrict__ edst,
    float* __restrict__ adjf, float* __restrict__ hnewf,
    unsigned short* __restrict__ bundle, unsigned short* __restrict__ WfT,
    unsigned short* __restrict__ WpT, unsigned short* __restrict__ sT,
    unsigned short* __restrict__ asT, unsigned short* __restrict__ featT,
    unsigned short* __restrict__ hT, unsigned short* __restrict__ Aadj,
    float* __restrict__ invdeg, unsigned int* __restrict__ Acnt) {
    __shared__ SMem sm;
    cg::grid_group grid = cg::this_grid();
    int tid = threadIdx.x;
    int gtid = blockIdx.x * 256 + tid;          // 0..65535

    // ---------------- P0: zero Acnt (8.4 MB) + d_out (17.8 MB) ----------------
    {
        uint4 z = {0u, 0u, 0u, 0u};
        uint4* A4 = reinterpret_cast<uint4*>(Acnt);       // 524288 uint4
        for (int i = gtid; i < 524288; i += GRID * 256) A4[i] = z;
        uint4* O4 = reinterpret_cast<uint4*>(adjf);       // 1114112 uint4
        for (int i = gtid; i < 1114112; i += GRID * 256) O4[i] = z;
    }
    __threadfence();
    grid.sync();

    // ---- P1: cast h -> bundle/hT (128) | edge count (1024) | W transposes (544) ----
    for (int t = blockIdx.x; t < 1696; t += GRID) {
        if (t < 128) {
            int node0 = t * 128;
            int r = tid >> 1, hf = tid & 1;
            const float4* h4 = reinterpret_cast<const float4*>(h + (size_t)(node0 + r) * 128 + hf * 64);
            unsigned short* bo = bundle + (size_t)(node0 + r) * 256 + hf * 64;
#pragma unroll
            for (int i = 0; i < 16; i++) {
                float4 v = h4[i];
                ushort4v o = { f2b(v.x), f2b(v.y), f2b(v.z), f2b(v.w) };
                *reinterpret_cast<ushort4v*>(bo + 4 * i) = o;
                int c = hf * 64 + 4 * i;
                sm.prep.fT[(c + 0) * 136 + r] = o.x;
                sm.prep.fT[(c + 1) * 136 + r] = o.y;
                sm.prep.fT[(c + 2) * 136 + r] = o.z;
                sm.prep.fT[(c + 3) * 136 + r] = o.w;
            }
            __syncthreads();
            int c = tid >> 1, nh = tid & 1;
            const uint4* src = reinterpret_cast<const uint4*>(&sm.prep.fT[c * 136 + nh * 64]);
            uint4* dst = reinterpret_cast<uint4*>(hT + (size_t)c * NN + node0 + nh * 64);
#pragma unroll
            for (int i = 0; i < 8; i++) dst[i] = src[i];
        } else if (t < 1152) {
            int e = (t - 128) * 256 + tid;
            int d = edst[e], sl = esrc[e] & 511;
            int idx = d * 512 + sl;
            atomicAdd(&Acnt[idx >> 2], 1u << (8 * (idx & 3)));
        } else {
            int tb = t - 1152;                 // 0..543 ; orig grid (68, 8)
            int bx = tb % 68, by = tb / 68;
            int tx = tid & 31, ty = tid >> 5;  // (32, 8)
            const float* in; unsigned short* out; int C, cb;
            if (bx < DD / 32) { in = Wf; out = WfT; C = DD; cb = bx; }
            else              { in = Wp; out = WpT; C = AS; cb = bx - DD / 32; }
            int c0 = cb * 32, r0 = by * 32;
            for (int i = 0; i < 4; i++)
                sm.tr.tl[ty + 8 * i][tx] = in[(size_t)(r0 + ty + 8 * i) * C + c0 + tx];
            __syncthreads();
            for (int i = 0; i < 4; i++)
                out[(size_t)(c0 + ty + 8 * i) * 256 + r0 + tx] = f2b(sm.tr.tl[tx][ty + 8 * i]);
        }
        __syncthreads();
    }
    __threadfence();
    grid.sync();

    // ---------------- P2: conv uint8 counts -> Aadj bf16 + invdeg ----------------
    for (int t = blockIdx.x; t < 2048; t += GRID) {
        int row = t * 8 + (tid >> 5);
        int u = tid & 31;
        uint4 w = reinterpret_cast<const uint4*>(Acnt)[(size_t)row * 32 + u];
        unsigned int wa[4] = { w.x, w.y, w.z, w.w };
        unsigned short out[16];
        float sum = 0.f;
#pragma unroll
        for (int i = 0; i < 4; i++) {
#pragma unroll
            for (int bb = 0; bb < 4; bb++) {
                float fv = (float)((wa[i] >> (8 * bb)) & 0xffu);
                sum += fv;
                out[4 * i + bb] = f2b(fv);
            }
        }
        unsigned int pw[8];
#pragma unroll
        for (int i = 0; i < 8; i++)
            pw[i] = (unsigned int)out[2 * i] | ((unsigned int)out[2 * i + 1] << 16);
        uint4* dst = reinterpret_cast<uint4*>(Aadj + (size_t)row * 512 + u * 16);
        uint4 s0 = { pw[0], pw[1], pw[2], pw[3] }, s1 = { pw[4], pw[5], pw[6], pw[7] };
        dst[0] = s0; dst[1] = s1;
#pragma unroll
        for (int d = 1; d < 32; d <<= 1) sum += __shfl_xor(sum, d, 64);
        if (u == 0) invdeg[row] = 1.0f / fmaxf(sum, 1.0f);
    }
    __threadfence();
    grid.sync();

    // ---------------- P3: agg_h via MFMA -> bundle upper half ----------------
    for (int bx = blockIdx.x; bx < 256; bx += GRID) {
        int r0 = bx * 64, g = bx >> 3;
        int wv = tid >> 6, lane = tid & 63, q = lane >> 4, lm = lane & 15;
        int mw = wv >> 1, nw = wv & 1;
#pragma unroll
        for (int j = 0; j < 16; j++) {
            int u = tid + 256 * j;
            int row = u >> 6, cu = (u & 63) ^ (row & 7);
            gload16(Aadj + (size_t)(r0 + row) * 512 + cu * 8, &sm.big[u * 8]);
        }
        floatx4 acc[2][4];
#pragma unroll
        for (int mt = 0; mt < 2; mt++)
#pragma unroll
            for (int nt = 0; nt < 4; nt++) acc[mt][nt] = (floatx4)0.f;
        __syncthreads();

        const unsigned short* Bb = hT + (size_t)(64 * nw + lm) * NN + g * 512 + (q << 3);
        short8 bF[2][4];
#pragma unroll
        for (int nt = 0; nt < 4; nt++)
            bF[0][nt] = *reinterpret_cast<const short8*>(Bb + (size_t)16 * nt * NN);
        for (int ki = 0; ki < 16; ki++) {
            if (ki < 15) {
#pragma unroll
                for (int nt = 0; nt < 4; nt++)
                    bF[(ki + 1) & 1][nt] =
                        *reinterpret_cast<const short8*>(Bb + (size_t)16 * nt * NN + (ki + 1) * 32);
            }
            short8 aF[2];
            int swz = (4 * ki + q) ^ (lm & 7);
#pragma unroll
            for (int mt = 0; mt < 2; mt++)
                aF[mt] = *reinterpret_cast<const short8*>(&sm.big[((32 * mw + 16 * mt + lm) * 64 + swz) * 8]);
#pragma unroll
            for (int mt = 0; mt < 2; mt++)
#pragma unroll
                for (int nt = 0; nt < 4; nt++)
                    acc[mt][nt] = __builtin_amdgcn_mfma_f32_16x16x32_bf16(aF[mt], bF[ki & 1][nt],
                                                                          acc[mt][nt], 0, 0, 0);
        }
#pragma unroll
        for (int mt = 0; mt < 2; mt++)
#pragma unroll
            for (int r = 0; r < 4; r++) {
                int row = 32 * mw + 16 * mt + 4 * q + r;
                float inv = invdeg[r0 + row];
#pragma unroll
                for (int nt = 0; nt < 4; nt++)
                    bundle[(size_t)(r0 + row) * 256 + 128 + 64 * nw + 16 * nt + lm] =
                        f2b(acc[mt][nt][r] * inv);
            }
        __syncthreads();
    }
    __threadfence();
    grid.sync();

    // ---------------- P4: feat GEMM (tasks 0-127) | pool fused (tasks 128-383) ----------------
    for (int t = blockIdx.x; t < 384; t += GRID) {
        if (t < 128) {
            // ---- feat: GEMM + bias + L2norm + relu -> featT ----
            int r0 = t * 128;
            int wv = tid >> 6, lane = tid & 63;
            int mw = wv >> 1, nw = wv & 1, q = lane >> 4, lm = lane & 15;
            int rowS0 = tid >> 2,         cS0 = (tid & 3) ^ ((rowS0 >> 1) & 3);
            int rowS1 = (tid + 256) >> 2, cS1 = ((tid + 256) & 3) ^ ((rowS1 >> 1) & 3);
            int swz = q ^ ((lm >> 1) & 3);
            floatx4 acc[4][4];
#pragma unroll
            for (int mi = 0; mi < 4; mi++)
#pragma unroll
                for (int ni = 0; ni < 4; ni++) acc[mi][ni] = (floatx4)0.f;
            for (int k0 = 0; k0 < 256; k0 += 32) {
                gload16(bundle + (size_t)(r0 + rowS0) * 256 + k0 + 8 * cS0, &sm.feat.lA[tid * 8]);
                gload16(bundle + (size_t)(r0 + rowS1) * 256 + k0 + 8 * cS1, &sm.feat.lA[(tid + 256) * 8]);
                gload16(WfT + (size_t)rowS0 * 256 + k0 + 8 * cS0, &sm.feat.lB[tid * 8]);
                gload16(WfT + (size_t)rowS1 * 256 + k0 + 8 * cS1, &sm.feat.lB[(tid + 256) * 8]);
                __syncthreads();
                short8 aF[4], bF[4];
#pragma unroll
                for (int mi = 0; mi < 4; mi++)
                    aF[mi] = *reinterpret_cast<const short8*>(&sm.feat.lA[((64 * mw + 16 * mi + lm) * 4 + swz) * 8]);
#pragma unroll
                for (int ni = 0; ni < 4; ni++)
                    bF[ni] = *reinterpret_cast<const short8*>(&sm.feat.lB[((64 * nw + 16 * ni + lm) * 4 + swz) * 8]);
#pragma unroll
                for (int mi = 0; mi < 4; mi++)
#pragma unroll
                    for (int ni = 0; ni < 4; ni++)
                        acc[mi][ni] = __builtin_amdgcn_mfma_f32_16x16x32_bf16(aF[mi], bF[ni], acc[mi][ni], 0, 0, 0);
                __syncthreads();
            }
#pragma unroll
            for (int ni = 0; ni < 4; ni++) {
                float bv = bfe[64 * nw + 16 * ni + lm];
#pragma unroll
                for (int mi = 0; mi < 4; mi++)
#pragma unroll
                    for (int r = 0; r < 4; r++) acc[mi][ni][r] += bv;
            }
#pragma unroll
            for (int mi = 0; mi < 4; mi++)
#pragma unroll
                for (int r = 0; r < 4; r++) {
                    float p = 0.f;
#pragma unroll
                    for (int ni = 0; ni < 4; ni++) p += acc[mi][ni][r] * acc[mi][ni][r];
                    p += __shfl_xor(p, 1, 64);
                    p += __shfl_xor(p, 2, 64);
                    p += __shfl_xor(p, 4, 64);
                    p += __shfl_xor(p, 8, 64);
                    if (lm == 0) sm.feat.red[nw * 128 + 64 * mw + 16 * mi + 4 * q + r] = p;
                }
            __syncthreads();
#pragma unroll
            for (int mi = 0; mi < 4; mi++) {
                float rrn[4];
#pragma unroll
                for (int r = 0; r < 4; r++) {
                    int rl = 64 * mw + 16 * mi + 4 * q + r;
                    rrn[r] = 1.0f / fmaxf(sqrtf(sm.feat.red[rl] + sm.feat.red[128 + rl]), 1e-12f);
                }
#pragma unroll
                for (int ni = 0; ni < 4; ni++) {
                    int col = 64 * nw + 16 * ni + lm;
                    ushort4v pk = { f2b(fmaxf(acc[mi][ni][0] * rrn[0], 0.f)),
                                    f2b(fmaxf(acc[mi][ni][1] * rrn[1], 0.f)),
                                    f2b(fmaxf(acc[mi][ni][2] * rrn[2], 0.f)),
                                    f2b(fmaxf(acc[mi][ni][3] * rrn[3], 0.f)) };
                    *reinterpret_cast<ushort4v*>(&sm.feat.fT[col * 136 + 64 * mw + 16 * mi + 4 * q]) = pk;
                }
            }
            __syncthreads();
            {
                int col = tid >> 1, half = tid & 1;
                const uint4* src = reinterpret_cast<const uint4*>(&sm.feat.fT[col * 136 + half * 64]);
                uint4* dst = reinterpret_cast<uint4*>(featT + (size_t)col * NN + r0 + half * 64);
#pragma unroll
                for (int i = 0; i < 8; i++) dst[i] = src[i];
            }
        } else {
            // ---- pool: A-resident GEMM + bias + ssq + norm + softmax -> sT ----
            int bx = t - 128;
            int r0 = bx * 64, g = bx >> 3;
            int wv = tid >> 6, lane = tid & 63, q = lane >> 4, lm = lane & 15;
#pragma unroll
            for (int j = 0; j < 8; j++) {
                int u = tid + 256 * j;
                int row = u >> 5;
                int chunk = (u & 31) ^ (row & 7);
                gload16(bundle + (size_t)(r0 + row) * 256 + chunk * 8, &sm.pool.lA[u * 8]);
            }
            float ssqacc[4][4];
#pragma unroll
            for (int mi = 0; mi < 4; mi++)
#pragma unroll
                for (int r = 0; r < 4; r++) ssqacc[mi][r] = 0.f;
            __syncthreads();
            for (int nc8 = 0; nc8 < 8; nc8++) {
                int nc = 4 * nc8 + wv;
                const unsigned short* Bb = WpT + ((size_t)(nc * 64 + lm) << 8) + (q << 3);
                short8 bF[2][4];
#pragma unroll
                for (int ni = 0; ni < 4; ni++)
                    bF[0][ni] = *reinterpret_cast<const short8*>(Bb + (ni << 12));
                floatx4 acc[4][4];
#pragma unroll
                for (int mi = 0; mi < 4; mi++)
#pragma unroll
                    for (int ni = 0; ni < 4; ni++) acc[mi][ni] = (floatx4)0.f;
#pragma unroll
                for (int k = 0; k < 8; k++) {
                    if (k < 7) {
#pragma unroll
                        for (int ni = 0; ni < 4; ni++)
                            bF[(k + 1) & 1][ni] =
                                *reinterpret_cast<const short8*>(Bb + (ni << 12) + ((k + 1) << 5));
                    }
                    short8 aF[4];
                    int swz = (4 * k + q) ^ (lm & 7);
#pragma unroll
                    for (int mi = 0; mi < 4; mi++)
                        aF[mi] = *reinterpret_cast<const short8*>(&sm.pool.lA[((16 * mi + lm) * 32 + swz) * 8]);
#pragma unroll
                    for (int mi = 0; mi < 4; mi++)
#pragma unroll
                        for (int ni = 0; ni < 4; ni++)
                            acc[mi][ni] = __builtin_amdgcn_mfma_f32_16x16x32_bf16(aF[mi], bF[k & 1][ni],
                                                                                  acc[mi][ni], 0, 0, 0);
                }
                float bv[4];
#pragma unroll
                for (int ni = 0; ni < 4; ni++) bv[ni] = bp[nc * 64 + 16 * ni + lm];
#pragma unroll
                for (int mi = 0; mi < 4; mi++)
#pragma unroll
                    for (int r = 0; r < 4; r++) {
                        float p = 0.f;
#pragma unroll
                        for (int ni = 0; ni < 4; ni++) {
                            acc[mi][ni][r] += bv[ni];
                            p += acc[mi][ni][r] * acc[mi][ni][r];
                        }
                        ssqacc[mi][r] += p;
                    }
                if (nc == g) {
#pragma unroll
                    for (int mi = 0; mi < 4; mi++)
#pragma unroll
                        for (int ni = 0; ni < 4; ni++)
#pragma unroll
                            for (int r = 0; r < 4; r++)
                                sm.pool.raw[(16 * mi + 4 * q + r) * 68 + 16 * ni + lm] = acc[mi][ni][r];
                }
            }
#pragma unroll
            for (int mi = 0; mi < 4; mi++)
#pragma unroll
                for (int r = 0; r < 4; r++) {
                    float p = ssqacc[mi][r];
                    p += __shfl_xor(p, 1, 64);
                    p += __shfl_xor(p, 2, 64);
                    p += __shfl_xor(p, 4, 64);
                    p += __shfl_xor(p, 8, 64);
                    if (lm == 0) sm.pool.ssq[wv * 64 + 16 * mi + 4 * q + r] = p;
                }
            __syncthreads();
            if (tid < 64)
                sm.pool.rn[tid] = 1.0f / fmaxf(sqrtf(sm.pool.ssq[tid] + sm.pool.ssq[64 + tid] +
                                               sm.pool.ssq[128 + tid] + sm.pool.ssq[192 + tid]), 1e-12f);
            __syncthreads();
            {
                int row = tid >> 2, j = tid & 3;
                int nloc = ((bx & 7) << 6) + row;
                float rn = sm.pool.rn[row];
                float v[16];
                float mx = -1e30f;
#pragma unroll
                for (int c4 = 0; c4 < 4; c4++) {
                    float4 rv = *reinterpret_cast<const float4*>(&sm.pool.raw[row * 68 + 16 * j + 4 * c4]);
                    v[4 * c4 + 0] = fmaxf(rv.x * rn, 0.f);
                    v[4 * c4 + 1] = fmaxf(rv.y * rn, 0.f);
                    v[4 * c4 + 2] = fmaxf(rv.z * rn, 0.f);
                    v[4 * c4 + 3] = fmaxf(rv.w * rn, 0.f);
                }
#pragma unroll
                for (int c = 0; c < 16; c++) mx = fmaxf(mx, v[c]);
                mx = fmaxf(mx, __shfl_xor(mx, 1, 64));
                mx = fmaxf(mx, __shfl_xor(mx, 2, 64));
                float z = 0.f;
#pragma unroll
                for (int c = 0; c < 16; c++) { v[c] = __expf(v[c] - mx); z += v[c]; }
                z += __shfl_xor(z, 1, 64);
                z += __shfl_xor(z, 2, 64);
                float iz = 1.0f / z;
#pragma unroll
                for (int c4 = 0; c4 < 4; c4++) {
                    size_t tb = (size_t)(g * KC + 16 * j + 4 * c4) * NPER + nloc;
                    sT[tb] = f2b(v[4 * c4 + 0] * iz);
                    sT[tb + NPER] = f2b(v[4 * c4 + 1] * iz);
                    sT[tb + 2 * NPER] = f2b(v[4 * c4 + 2] * iz);
                    sT[tb + 3 * NPER] = f2b(v[4 * c4 + 3] * iz);
                }
            }
        }
        __syncthreads();
    }
    __threadfence();
    grid.sync();

    // ---------------- P5: a_s via MFMA -> asT ----------------
    for (int bx = blockIdx.x; bx < NB * 2; bx += GRID) {
        int g = bx >> 1, half = bx & 1;
        int wv = tid >> 6, lane = tid & 63, q = lane >> 4, lm = lane & 15;
#pragma unroll
        for (int j = 0; j < 16; j++) {
            int u = tid + 256 * j;
            int row = u >> 6, cu = (u & 63) ^ (row & 7);
            gload16(sT + (size_t)(g * KC + row) * NPER + cu * 8, &sm.big[u * 8]);
        }
        floatx4 acc[4][4];
#pragma unroll
        for (int mi = 0; mi < 4; mi++)
#pragma unroll
            for (int nt = 0; nt < 4; nt++) acc[mi][nt] = (floatx4)0.f;
        __syncthreads();

        int dbase = half * 256 + wv * 64;
        const unsigned short* Bb = Aadj + (size_t)(g * 512 + dbase + lm) * 512 + (q << 3);
        short8 bF[2][4];
#pragma unroll
        for (int nt = 0; nt < 4; nt++)
            bF[0][nt] = *reinterpret_cast<const short8*>(Bb + (size_t)16 * nt * 512);
        for (int ki = 0; ki < 16; ki++) {
            if (ki < 15) {
#pragma unroll
                for (int nt = 0; nt < 4; nt++)
                    bF[(ki + 1) & 1][nt] =
                        *reinterpret_cast<const short8*>(Bb + (size_t)16 * nt * 512 + (ki + 1) * 32);
            }
            short8 aF[4];
            int swz = (4 * ki + q) ^ (lm & 7);
#pragma unroll
            for (int mi = 0; mi < 4; mi++)
                aF[mi] = *reinterpret_cast<const short8*>(&sm.big[((16 * mi + lm) * 64 + swz) * 8]);
#pragma unroll
            for (int mi = 0; mi < 4; mi++)
#pragma unroll
                for (int nt = 0; nt < 4; nt++)
                    acc[mi][nt] = __builtin_amdgcn_mfma_f32_16x16x32_bf16(aF[mi], bF[ki & 1][nt],
                                                                          acc[mi][nt], 0, 0, 0);
        }
#pragma unroll
        for (int mi = 0; mi < 4; mi++)
#pragma unroll
            for (int r = 0; r < 4; r++) {
                int row = 16 * mi + 4 * q + r;
#pragma unroll
                for (int nt = 0; nt < 4; nt++)
                    asT[(size_t)(g * KC + row) * NPER + dbase + 16 * nt + lm] = f2b(acc[mi][nt][r]);
            }
        __syncthreads();
    }
    __threadfence();
    grid.sync();

    // ---------------- P6: fused h_new + adj via MFMA ----------------
    for (int t = blockIdx.x; t < 128; t += GRID) {
        int ch = t & 3, g = t >> 2;
        int k0 = g * NPER + ch * 128;
        int wv = tid >> 6, lane = tid & 63, q = lane >> 4, lm = lane & 15;
#pragma unroll
        for (int j = 0; j < 4; j++) {
            int u = tid + 256 * j;
            int row = u >> 4, cu = (u & 15) ^ (row & 15);
            gload16(sT + (size_t)(g * KC + row) * NPER + ch * 128 + cu * 8, &sm.ha.lS[u * 8]);
        }
#pragma unroll
        for (int j = 0; j < 8; j++) {
            int u = tid + 256 * j;
            int row = u >> 4, cu = (u & 15) ^ (row & 15);
            gload16(featT + (size_t)row * NN + k0 + cu * 8, &sm.ha.lF[u * 8]);
        }
#pragma unroll
        for (int j = 0; j < 4; j++) {
            int u = tid + 256 * j;
            int row = u >> 4, cu = (u & 15) ^ (row & 15);
            gload16(asT + (size_t)(g * KC + row) * NPER + ch * 128 + cu * 8, &sm.ha.lAS[u * 8]);
        }
        floatx4 acc[4][4];
#pragma unroll
        for (int mi = 0; mi < 4; mi++)
#pragma unroll
            for (int ni = 0; ni < 4; ni++) acc[mi][ni] = (floatx4)0.f;
        __syncthreads();

        bool isH = (wv < 2);
        for (int ks = 0; ks < 4; ks++) {
            if (!isH && (ks >> 1) != (wv & 1)) continue;
            short8 aF[4], bF[4];
#pragma unroll
            for (int mi = 0; mi < 4; mi++)
                aF[mi] = *reinterpret_cast<const short8*>(
                    &sm.ha.lS[((16 * mi + lm) * 16 + ((4 * ks + q) ^ lm)) * 8]);
            if (isH) {
#pragma unroll
                for (int ni = 0; ni < 4; ni++)
                    bF[ni] = *reinterpret_cast<const short8*>(
                        &sm.ha.lF[((64 * wv + 16 * ni + lm) * 16 + ((4 * ks + q) ^ lm)) * 8]);
            } else {
#pragma unroll
                for (int ni = 0; ni < 4; ni++)
                    bF[ni] = *reinterpret_cast<const short8*>(
                        &sm.ha.lAS[((16 * ni + lm) * 16 + ((4 * ks + q) ^ lm)) * 8]);
            }
#pragma unroll
            for (int mi = 0; mi < 4; mi++)
#pragma unroll
                for (int ni = 0; ni < 4; ni++)
                    acc[mi][ni] = __builtin_amdgcn_mfma_f32_16x16x32_bf16(aF[mi], bF[ni], acc[mi][ni], 0, 0, 0);
        }
        if (isH) {
#pragma unroll
            for (int mi = 0; mi < 4; mi++)
#pragma unroll
                for (int ni = 0; ni < 4; ni++)
#pragma unroll
                    for (int r = 0; r < 4; r++)
                        atomicAdd(&hnewf[(size_t)(g * KC + 16 * mi + 4 * q + r) * DD +
                                         64 * wv + 16 * ni + lm], acc[mi][ni][r]);
        } else {
#pragma unroll
            for (int mi = 0; mi < 4; mi++)
#pragma unroll
                for (int ni = 0; ni < 4; ni++)
#pragma unroll
                    for (int r = 0; r < 4; r++)
                        atomicAdd(&adjf[(size_t)(g * KC + 16 * mi + 4 * q + r) * AS +
                                        g * KC + 16 * ni + lm], acc[mi][ni][r]);
        }
        __syncthreads();
    }
}

// ================= fallback path: R7 multi-kernel (known-good, 185.7 µs) =================

__global__ void prep_kernel(const float* __restrict__ h, unsigned short* __restrict__ bundle,
                            unsigned short* __restrict__ hT, const int* __restrict__ esrc,
                            const int* __restrict__ edst, unsigned int* __restrict__ Acnt) {
    __shared__ unsigned short fT[128 * 136];
    int b = blockIdx.x, t = threadIdx.x;
    if (b < 128) {
        int node0 = b * 128;
        int r = t >> 1, hf = t & 1;
        const float4* h4 = reinterpret_cast<const float4*>(h + (size_t)(node0 + r) * 128 + hf * 64);
        unsigned short* bo = bundle + (size_t)(node0 + r) * 256 + hf * 64;
#pragma unroll
        for (int i = 0; i < 16; i++) {
            float4 v = h4[i];
            ushort4v o = { f2b(v.x), f2b(v.y), f2b(v.z), f2b(v.w) };
            *reinterpret_cast<ushort4v*>(bo + 4 * i) = o;
            int c = hf * 64 + 4 * i;
            fT[(c + 0) * 136 + r] = o.x;
            fT[(c + 1) * 136 + r] = o.y;
            fT[(c + 2) * 136 + r] = o.z;
            fT[(c + 3) * 136 + r] = o.w;
        }
        __syncthreads();
        int c = t >> 1, nh = t & 1;
        const uint4* src = reinterpret_cast<const uint4*>(&fT[c * 136 + nh * 64]);
        uint4* dst = reinterpret_cast<uint4*>(hT + (size_t)c * NN + node0 + nh * 64);
#pragma unroll
        for (int i = 0; i < 8; i++) dst[i] = src[i];
    } else {
        int e = (b - 128) * 256 + t;
        int d = edst[e], sl = esrc[e] & 511;
        int idx = d * 512 + sl;
        atomicAdd(&Acnt[idx >> 2], 1u << (8 * (idx & 3)));
    }
}

__global__ void conv_kernel(const unsigned int* __restrict__ Acnt,
                            unsigned short* __restrict__ Aadj, float* __restrict__ invdeg) {
    int t = threadIdx.x;
    int row = blockIdx.x * 8 + (t >> 5);
    int u = t & 31;
    uint4 w = reinterpret_cast<const uint4*>(Acnt)[(size_t)row * 32 + u];
    unsigned int wa[4] = { w.x, w.y, w.z, w.w };
    unsigned short out[16];
    float sum = 0.f;
#pragma unroll
    for (int i = 0; i < 4; i++) {
#pragma unroll
        for (int bb = 0; bb < 4; bb++) {
            float fv = (float)((wa[i] >> (8 * bb)) & 0xffu);
            sum += fv;
            out[4 * i + bb] = f2b(fv);
        }
    }
    unsigned int pw[8];
#pragma unroll
    for (int i = 0; i < 8; i++)
        pw[i] = (unsigned int)out[2 * i] | ((unsigned int)out[2 * i + 1] << 16);
    uint4* dst = reinterpret_cast<uint4*>(Aadj + (size_t)row * 512 + u * 16);
    uint4 s0 = { pw[0], pw[1], pw[2], pw[3] }, s1 = { pw[4], pw[5], pw[6], pw[7] };
    dst[0] = s0; dst[1] = s1;
#pragma unroll
    for (int d = 1; d < 32; d <<= 1) sum += __shfl_xor(sum, d, 64);
    if (u == 0) invdeg[row] = 1.0f / fmaxf(sum, 1.0f);
}

__global__ void transpose_cast2_kernel(const float* __restrict__ Wf, const float* __restrict__ Wp,
                                       unsigned short* __restrict__ WfT, unsigned short* __restrict__ WpT) {
    __shared__ float tl[32][33];
    int tx = threadIdx.x, ty = threadIdx.y;
    int bx = blockIdx.x;
    const float* in; unsigned short* out; int C, cb;
    if (bx < DD / 32) { in = Wf; out = WfT; C = DD; cb = bx; }
    else              { in = Wp; out = WpT; C = AS; cb = bx - DD / 32; }
    int c0 = cb * 32, r0 = blockIdx.y * 32;
    for (int i = 0; i < 4; i++)
        tl[ty + 8 * i][tx] = in[(size_t)(r0 + ty + 8 * i) * C + c0 + tx];
    __syncthreads();
    for (int i = 0; i < 4; i++)
        out[(size_t)(c0 + ty + 8 * i) * 256 + r0 + tx] = f2b(tl[tx][ty + 8 * i]);
}

__global__ __launch_bounds__(256) void agg_h_mfma_kernel(
    const unsigned short* __restrict__ Aadj, const unsigned short* __restrict__ hT,
    const float* __restrict__ invdeg, unsigned short* __restrict__ bundle) {
    __shared__ alignas(16) unsigned short lA[64 * 512];
    int tid = threadIdx.x, bx = blockIdx.x;
    int r0 = bx * 64, g = bx >> 3;
    int wv = tid >> 6, lane = tid & 63, q = lane >> 4, lm = lane & 15;
    int mw = wv >> 1, nw = wv & 1;
#pragma unroll
    for (int j = 0; j < 16; j++) {
        int u = tid + 256 * j;
        int row = u >> 6, cu = (u & 63) ^ (row & 7);
        gload16(Aadj + (size_t)(r0 + row) * 512 + cu * 8, &lA[u * 8]);
    }
    floatx4 acc[2][4];
#pragma unroll
    for (int mt = 0; mt < 2; mt++)
#pragma unroll
        for (int nt = 0; nt < 4; nt++) acc[mt][nt] = (floatx4)0.f;
    __syncthreads();
    const unsigned short* Bb = hT + (size_t)(64 * nw + lm) * NN + g * 512 + (q << 3);
    short8 bF[2][4];
#pragma unroll
    for (int nt = 0; nt < 4; nt++)
        bF[0][nt] = *reinterpret_cast<const short8*>(Bb + (size_t)16 * nt * NN);
    for (int ki = 0; ki < 16; ki++) {
        if (ki < 15) {
#pragma unroll
            for (int nt = 0; nt < 4; nt++)
                bF[(ki + 1) & 1][nt] =
                    *reinterpret_cast<const short8*>(Bb + (size_t)16 * nt * NN + (ki + 1) * 32);
        }
        short8 aF[2];
        int swz = (4 * ki + q) ^ (lm & 7);
#pragma unroll
        for (int mt = 0; mt < 2; mt++)
            aF[mt] = *reinterpret_cast<const short8*>(&lA[((32 * mw + 16 * mt + lm) * 64 + swz) * 8]);
#pragma unroll
        for (int mt = 0; mt < 2; mt++)
#pragma unroll
            for (int nt = 0; nt < 4; nt++)
                acc[mt][nt] = __builtin_amdgcn_mfma_f32_16x16x32_bf16(aF[mt], bF[ki & 1][nt],
                                                                      acc[mt][nt], 0, 0, 0);
    }
#pragma unroll
    for (int mt = 0; mt < 2; mt++)
#pragma unroll
        for (int r = 0; r < 4; r++) {
            int row = 32 * mw + 16 * mt + 4 * q + r;
            float inv = invdeg[r0 + row];
#pragma unroll
            for (int nt = 0; nt < 4; nt++)
                bundle[(size_t)(r0 + row) * 256 + 128 + 64 * nw + 16 * nt + lm] =
                    f2b(acc[mt][nt][r] * inv);
        }
}

__global__ __launch_bounds__(256) void feat_mfma_kernel(
    const unsigned short* __restrict__ bundle, const unsigned short* __restrict__ WfT,
    const float* __restrict__ bfe, unsigned short* __restrict__ featT) {
    __shared__ alignas(16) unsigned short lA[512 * 8];
    __shared__ alignas(16) unsigned short lB[512 * 8];
    __shared__ float red[256];
    __shared__ alignas(16) unsigned short fT[128 * 136];
    int tid = threadIdx.x;
    int r0 = blockIdx.x * 128;
    int wv = tid >> 6, lane = tid & 63;
    int mw = wv >> 1, nw = wv & 1, q = lane >> 4, lm = lane & 15;
    int rowS0 = tid >> 2,         cS0 = (tid & 3) ^ ((rowS0 >> 1) & 3);
    int rowS1 = (tid + 256) >> 2, cS1 = ((tid + 256) & 3) ^ ((rowS1 >> 1) & 3);
    int swz = q ^ ((lm >> 1) & 3);
    floatx4 acc[4][4];
#pragma unroll
    for (int mi = 0; mi < 4; mi++)
#pragma unroll
        for (int ni = 0; ni < 4; ni++) acc[mi][ni] = (floatx4)0.f;
    for (int k0 = 0; k0 < 256; k0 += 32) {
        gload16(bundle + (size_t)(r0 + rowS0) * 256 + k0 + 8 * cS0, &lA[tid * 8]);
        gload16(bundle + (size_t)(r0 + rowS1) * 256 + k0 + 8 * cS1, &lA[(tid + 256) * 8]);
        gload16(WfT + (size_t)rowS0 * 256 + k0 + 8 * cS0, &lB[tid * 8]);
        gload16(WfT + (size_t)rowS1 * 256 + k0 + 8 * cS1, &lB[(tid + 256) * 8]);
        __syncthreads();
        short8 aF[4], bF[4];
#pragma unroll
        for (int mi = 0; mi < 4; mi++)
            aF[mi] = *reinterpret_cast<const short8*>(&lA[((64 * mw + 16 * mi + lm) * 4 + swz) * 8]);
#pragma unroll
        for (int ni = 0; ni < 4; ni++)
            bF[ni] = *reinterpret_cast<const short8*>(&lB[((64 * nw + 16 * ni + lm) * 4 + swz) * 8]);
#pragma unroll
        for (int mi = 0; mi < 4; mi++)
#pragma unroll
            for (int ni = 0; ni < 4; ni++)
                acc[mi][ni] = __builtin_amdgcn_mfma_f32_16x16x32_bf16(aF[mi], bF[ni], acc[mi][ni], 0, 0, 0);
        __syncthreads();
    }
#pragma unroll
    for (int ni = 0; ni < 4; ni++) {
        float bv = bfe[64 * nw + 16 * ni + lm];
#pragma unroll
        for (int mi = 0; mi < 4; mi++)
#pragma unroll
            for (int r = 0; r < 4; r++) acc[mi][ni][r] += bv;
    }
#pragma unroll
    for (int mi = 0; mi < 4; mi++)
#pragma unroll
        for (int r = 0; r < 4; r++) {
            float p = 0.f;
#pragma unroll
            for (int ni = 0; ni < 4; ni++) p += acc[mi][ni][r] * acc[mi][ni][r];
            p += __shfl_xor(p, 1, 64);
            p += __shfl_xor(p, 2, 64);
            p += __shfl_xor(p, 4, 64);
            p += __shfl_xor(p, 8, 64);
            if (lm == 0) red[nw * 128 + 64 * mw + 16 * mi + 4 * q + r] = p;
        }
    __syncthreads();
#pragma unroll
    for (int mi = 0; mi < 4; mi++) {
        float rrn[4];
#pragma unroll
        for (int r = 0; r < 4; r++) {
            int rl = 64 * mw + 16 * mi + 4 * q + r;
            rrn[r] = 1.0f / fmaxf(sqrtf(red[rl] + red[128 + rl]), 1e-12f);
        }
#pragma unroll
        for (int ni = 0; ni < 4; ni++) {
            int col = 64 * nw + 16 * ni + lm;
            ushort4v pk = { f2b(fmaxf(acc[mi][ni][0] * rrn[0], 0.f)),
                            f2b(fmaxf(acc[mi][ni][1] * rrn[1], 0.f)),
                            f2b(fmaxf(acc[mi][ni][2] * rrn[2], 0.f)),
                            f2b(fmaxf(acc[mi][ni][3] * rrn[3], 0.f)) };
            *reinterpret_cast<ushort4v*>(&fT[col * 136 + 64 * mw + 16 * mi + 4 * q]) = pk;
        }
    }
    __syncthreads();
    {
        int col = tid >> 1, half = tid & 1;
        const uint4* src = reinterpret_cast<const uint4*>(&fT[col * 136 + half * 64]);
        uint4* dst = reinterpret_cast<uint4*>(featT + (size_t)col * NN + r0 + half * 64);
#pragma unroll
        for (int i = 0; i < 8; i++) dst[i] = src[i];
    }
}

__global__ __launch_bounds__(256) void pool_fused_kernel(
    const unsigned short* __restrict__ bundle, const unsigned short* __restrict__ WpT,
    const float* __restrict__ bp, unsigned short* __restrict__ sT) {
    __shared__ alignas(16) unsigned short lA[2048 * 8];
    __shared__ float raw[64 * 68];
    __shared__ float ssq_l[4 * 64];
    __shared__ float rn_l[64];
    int tid = threadIdx.x, bx = blockIdx.x;
    int r0 = bx * 64, g = bx >> 3;
    int wv = tid >> 6, lane = tid & 63, q = lane >> 4, lm = lane & 15;
#pragma unroll
    for (int j = 0; j < 8; j++) {
        int u = tid + 256 * j;
        int row = u >> 5;
        int chunk = (u & 31) ^ (row & 7);
        gload16(bundle + (size_t)(r0 + row) * 256 + chunk * 8, &lA[u * 8]);
    }
    float ssqacc[4][4];
#pragma unroll
    for (int mi = 0; mi < 4; mi++)
#pragma unroll
        for (int r = 0; r < 4; r++) ssqacc[mi][r] = 0.f;
    __syncthreads();
    for (int nc8 = 0; nc8 < 8; nc8++) {
        int nc = 4 * nc8 + wv;
        const unsigned short* Bb = WpT + ((size_t)(nc * 64 + lm) << 8) + (q << 3);
        short8 bF[2][4];
#pragma unroll
        for (int ni = 0; ni < 4; ni++)
            bF[0][ni] = *reinterpret_cast<const short8*>(Bb + (ni << 12));
        floatx4 acc[4][4];
#pragma unroll
        for (int mi = 0; mi < 4; mi++)
#pragma unroll
            for (int ni = 0; ni < 4; ni++) acc[mi][ni] = (floatx4)0.f;
#pragma unroll
        for (int k = 0; k < 8; k++) {
            if (k < 7) {
#pragma unroll
                for (int ni = 0; ni < 4; ni++)
                    bF[(k + 1) & 1][ni] =
                        *reinterpret_cast<const short8*>(Bb + (ni << 12) + ((k + 1) << 5));
            }
            short8 aF[4];
            int swz = (4 * k + q) ^ (lm & 7);
#pragma unroll
            for (int mi = 0; mi < 4; mi++)
                aF[mi] = *reinterpret_cast<const short8*>(&lA[((16 * mi + lm) * 32 + swz) * 8]);
#pragma unroll
            for (int mi = 0; mi < 4; mi++)
#pragma unroll
                for (int ni = 0; ni < 4; ni++)
                    acc[mi][ni] = __builtin_amdgcn_mfma_f32_16x16x32_bf16(aF[mi], bF[k & 1][ni],
                                                                          acc[mi][ni], 0, 0, 0);
        }
        float bv[4];
#pragma unroll
        for (int ni = 0; ni < 4; ni++) bv[ni] = bp[nc * 64 + 16 * ni + lm];
#pragma unroll
        for (int mi = 0; mi < 4; mi++)
#pragma unroll
            for (int r = 0; r < 4; r++) {
                float p = 0.f;
#pragma unroll
                for (int ni = 0; ni < 4; ni++) {
                    acc[mi][ni][r] += bv[ni];
                    p += acc[mi][ni][r] * acc[mi][ni][r];
                }
                ssqacc[mi][r] += p;
            }
        if (nc == g) {
#pragma unroll
            for (int mi = 0; mi < 4; mi++)
#pragma unroll
                for (int ni = 0; ni < 4; ni++)
#pragma unroll
                    for (int r = 0; r < 4; r++)
                        raw[(16 * mi + 4 * q + r) * 68 + 16 * ni + lm] = acc[mi][ni][r];
        }
    }
#pragma unroll
    for (int mi = 0; mi < 4; mi++)
#pragma unroll
        for (int r = 0; r < 4; r++) {
            float p = ssqacc[mi][r];
            p += __shfl_xor(p, 1, 64);
            p += __shfl_xor(p, 2, 64);
            p += __shfl_xor(p, 4, 64);
            p += __shfl_xor(p, 8, 64);
            if (lm == 0) ssq_l[wv * 64 + 16 * mi + 4 * q + r] = p;
        }
    __syncthreads();
    if (tid < 64)
        rn_l[tid] = 1.0f / fmaxf(sqrtf(ssq_l[tid] + ssq_l[64 + tid] + ssq_l[128 + tid] +
                                       ssq_l[192 + tid]), 1e-12f);
    __syncthreads();
    {
        int row = tid >> 2, j = tid & 3;
        int nloc = ((bx & 7) << 6) + row;
        float rn = rn_l[row];
        float v[16];
        float mx = -1e30f;
#pragma unroll
        for (int c4 = 0; c4 < 4; c4++) {
            float4 rv = *reinterpret_cast<const float4*>(&raw[row * 68 + 16 * j + 4 * c4]);
            v[4 * c4 + 0] = fmaxf(rv.x * rn, 0.f);
            v[4 * c4 + 1] = fmaxf(rv.y * rn, 0.f);
            v[4 * c4 + 2] = fmaxf(rv.z * rn, 0.f);
            v[4 * c4 + 3] = fmaxf(rv.w * rn, 0.f);
        }
#pragma unroll
        for (int c = 0; c < 16; c++) mx = fmaxf(mx, v[c]);
        mx = fmaxf(mx, __shfl_xor(mx, 1, 64));
        mx = fmaxf(mx, __shfl_xor(mx, 2, 64));
        float z = 0.f;
#pragma unroll
        for (int c = 0; c < 16; c++) { v[c] = __expf(v[c] - mx); z += v[c]; }
        z += __shfl_xor(z, 1, 64);
        z += __shfl_xor(z, 2, 64);
        float iz = 1.0f / z;
#pragma unroll
        for (int c4 = 0; c4 < 4; c4++) {
            size_t tb = (size_t)(g * KC + 16 * j + 4 * c4) * NPER + nloc;
            sT[tb] = f2b(v[4 * c4 + 0] * iz);
            sT[tb + NPER] = f2b(v[4 * c4 + 1] * iz);
            sT[tb + 2 * NPER] = f2b(v[4 * c4 + 2] * iz);
            sT[tb + 3 * NPER] = f2b(v[4 * c4 + 3] * iz);
        }
    }
}

__global__ __launch_bounds__(256) void as_mfma_kernel(
    const unsigned short* __restrict__ sT, const unsigned short* __restrict__ Aadj,
    unsigned short* __restrict__ asT) {
    __shared__ alignas(16) unsigned short lS[64 * 512];
    int tid = threadIdx.x, bx = blockIdx.x;
    int g = bx >> 1, half = bx & 1;
    int wv = tid >> 6, lane = tid & 63, q = lane >> 4, lm = lane & 15;
#pragma unroll
    for (int j = 0; j < 16; j++) {
        int u = tid + 256 * j;
        int row = u >> 6, cu = (u & 63) ^ (row & 7);
        gload16(sT + (size_t)(g * KC + row) * NPER + cu * 8, &lS[u * 8]);
    }
    floatx4 acc[4][4];
#pragma unroll
    for (int mi = 0; mi < 4; mi++)
#pragma unroll
        for (int nt = 0; nt < 4; nt++) acc[mi][nt] = (floatx4)0.f;
    __syncthreads();
    int dbase = half * 256 + wv * 64;
    const unsigned short* Bb = Aadj + (size_t)(g * 512 + dbase + lm) * 512 + (q << 3);
    short8 bF[2][4];
#pragma unroll
    for (int nt = 0; nt < 4; nt++)
        bF[0][nt] = *reinterpret_cast<const short8*>(Bb + (size_t)16 * nt * 512);
    for (int ki = 0; ki < 16; ki++) {
        if (ki < 15) {
#pragma unroll
            for (int nt = 0; nt < 4; nt++)
                bF[(ki + 1) & 1][nt] =
                    *reinterpret_cast<const short8*>(Bb + (size_t)16 * nt * 512 + (ki + 1) * 32);
        }
        short8 aF[4];
        int swz = (4 * ki + q) ^ (lm & 7);
#pragma unroll
        for (int mi = 0; mi < 4; mi++)
            aF[mi] = *reinterpret_cast<const short8*>(&lS[((16 * mi + lm) * 64 + swz) * 8]);
#pragma unroll
        for (int mi = 0; mi < 4; mi++)
#pragma unroll
            for (int nt = 0; nt < 4; nt++)
                acc[mi][nt] = __builtin_amdgcn_mfma_f32_16x16x32_bf16(aF[mi], bF[ki & 1][nt],
                                                                      acc[mi][nt], 0, 0, 0);
    }
#pragma unroll
    for (int mi = 0; mi < 4; mi++)
#pragma unroll
        for (int r = 0; r < 4; r++) {
            int row = 16 * mi + 4 * q + r;
#pragma unroll
            for (int nt = 0; nt < 4; nt++)
                asT[(size_t)(g * KC + row) * NPER + dbase + 16 * nt + lm] = f2b(acc[mi][nt][r]);
        }
}

__global__ __launch_bounds__(256) void hnew_adj_kernel(
    const unsigned short* __restrict__ sT, const unsigned short* __restrict__ featT,
    const unsigned short* __restrict__ asT, float* __restrict__ adjf,
    float* __restrict__ hnewf) {
    __shared__ alignas(16) unsigned short lS[1024 * 8];
    __shared__ alignas(16) unsigned short lF[2048 * 8];
    __shared__ alignas(16) unsigned short lAS[1024 * 8];
    int tid = threadIdx.x;
    int ch = blockIdx.x, g = blockIdx.y;
    int k0 = g * NPER + ch * 128;
    int wv = tid >> 6, lane = tid & 63, q = lane >> 4, lm = lane & 15;
#pragma unroll
    for (int j = 0; j < 4; j++) {
        int u = tid + 256 * j;
        int row = u >> 4, cu = (u & 15) ^ (row & 15);
        gload16(sT + (size_t)(g * KC + row) * NPER + ch * 128 + cu * 8, &lS[u * 8]);
    }
#pragma unroll
    for (int j = 0; j < 8; j++) {
        int u = tid + 256 * j;
        int row = u >> 4, cu = (u & 15) ^ (row & 15);
        gload16(featT + (size_t)row * NN + k0 + cu * 8, &lF[u * 8]);
    }
#pragma unroll
    for (int j = 0; j < 4; j++) {
        int u = tid + 256 * j;
        int row = u >> 4, cu = (u & 15) ^ (row & 15);
        gload16(asT + (size_t)(g * KC + row) * NPER + ch * 128 + cu * 8, &lAS[u * 8]);
    }
    floatx4 acc[4][4];
#pragma unroll
    for (int mi = 0; mi < 4; mi++)
#pragma unroll
        for (int ni = 0; ni < 4; ni++) acc[mi][ni] = (floatx4)0.f;
    __syncthreads();
    bool isH = (wv < 2);
    for (int ks = 0; ks < 4; ks++) {
        if (!isH && (ks >> 1) != (wv & 1)) continue;
        short8 aF[4], bF[4];
#pragma unroll
        for (int mi = 0; mi < 4; mi++)
            aF[mi] = *reinterpret_cast<const short8*>(
                &lS[((16 * mi + lm) * 16 + ((4 * ks + q) ^ lm)) * 8]);
        if (isH) {
#pragma unroll
            for (int ni = 0; ni < 4; ni++)
                bF[ni] = *reinterpret_cast<const short8*>(
                    &lF[((64 * wv + 16 * ni + lm) * 16 + ((4 * ks + q) ^ lm)) * 8]);
        } else {
#pragma unroll
            for (int ni = 0; ni < 4; ni++)
                bF[ni] = *reinterpret_cast<const short8*>(
                    &lAS[((16 * ni + lm) * 16 + ((4 * ks + q) ^ lm)) * 8]);
        }
#pragma unroll
        for (int mi = 0; mi < 4; mi++)
#pragma unroll
            for (int ni = 0; ni < 4; ni++)
                acc[mi][ni] = __builtin_amdgcn_mfma_f32_16x16x32_bf16(aF[mi], bF[ni], acc[mi][ni], 0, 0, 0);
    }
    if (isH) {
#pragma unroll
        for (int mi = 0; mi < 4; mi++)
#pragma unroll
            for (int ni = 0; ni < 4; ni++)
#pragma unroll
                for (int r = 0; r < 4; r++)
                    atomicAdd(&hnewf[(size_t)(g * KC + 16 * mi + 4 * q + r) * DD +
                                     64 * wv + 16 * ni + lm], acc[mi][ni][r]);
    } else {
#pragma unroll
        for (int mi = 0; mi < 4; mi++)
#pragma unroll
            for (int ni = 0; ni < 4; ni++)
#pragma unroll
                for (int r = 0; r < 4; r++)
                    atomicAdd(&adjf[(size_t)(g * KC + 16 * mi + 4 * q + r) * AS +
                                    g * KC + 16 * ni + lm], acc[mi][ni][r]);
    }
}

extern "C" void kernel_launch(void* const* d_in, const int* in_sizes, int n_in,
                              void* d_out, int out_size, void* d_ws, size_t ws_size,
                              hipStream_t stream) {
    const float* h   = (const float*)d_in[0];
    const float* Wf  = (const float*)d_in[1];
    const float* bfe = (const float*)d_in[2];
    const float* Wp  = (const float*)d_in[3];
    const float* bp  = (const float*)d_in[4];
    const int* esrc  = (const int*)d_in[5];
    const int* edst  = (const int*)d_in[6];

    float* adjf  = (float*)d_out;
    float* hnewf = adjf + (size_t)AS * AS;

    unsigned short* bundle = (unsigned short*)d_ws;        // NN*256 bf16
    unsigned short* WfT   = bundle + (size_t)NN * 256;     // 128*256
    unsigned short* WpT   = WfT + 128 * 256;               // 2048*256
    unsigned short* sT    = WpT + (size_t)AS * 256;        // NN*KC
    unsigned short* asT   = sT + (size_t)NN * KC;          // NN*KC
    unsigned short* featT = asT + (size_t)NN * KC;         // DD*NN
    unsigned short* hT    = featT + (size_t)DD * NN;       // DD*NN
    unsigned short* Aadj  = hT + (size_t)DD * NN;          // NN*512 bf16 (16 MB)
    float* invdeg = (float*)(Aadj + (size_t)NN * 512);     // NN
    unsigned int* Acnt = (unsigned int*)(invdeg + NN);     // NN*512 bytes (8.4 MB)

    void* kargs[] = { (void*)&h, (void*)&Wf, (void*)&bfe, (void*)&Wp, (void*)&bp,
                      (void*)&esrc, (void*)&edst, (void*)&adjf, (void*)&hnewf,
                      (void*)&bundle, (void*)&WfT, (void*)&WpT, (void*)&sT, (void*)&asT,
                      (void*)&featT, (void*)&hT, (void*)&Aadj, (void*)&invdeg, (void*)&Acnt };
    hipError_t err = hipLaunchCooperativeKernel((void*)mega_kernel, dim3(GRID), dim3(256),
                                                kargs, 0, stream);
    if (err != hipSuccess) {
        // fallback: proven R7 multi-kernel path (same math)
        hipMemsetAsync(Acnt, 0, (size_t)NN * 512, stream);
        hipMemsetAsync(d_out, 0, ((size_t)AS * AS + (size_t)AS * DD) * sizeof(float), stream);
        prep_kernel<<<128 + EE / 256, 256, 0, stream>>>(h, bundle, hT, esrc, edst, Acnt);
        conv_kernel<<<NN / 8, 256, 0, stream>>>(Acnt, Aadj, invdeg);
        transpose_cast2_kernel<<<dim3(DD / 32 + AS / 32, 256 / 32), dim3(32, 8), 0, stream>>>(
            Wf, Wp, WfT, WpT);
        agg_h_mfma_kernel<<<NN / 64, 256, 0, stream>>>(Aadj, hT, invdeg, bundle);
        feat_mfma_kernel<<<NN / 128, 256, 0, stream>>>(bundle, WfT, bfe, featT);
        pool_fused_kernel<<<NN / 64, 256, 0, stream>>>(bundle, WpT, bp, sT);
        as_mfma_kernel<<<NB * 2, 256, 0, stream>>>(sT, Aadj, asT);
        hnew_adj_kernel<<<dim3(4, NB), 256, 0, stream>>>(sT, featT, asT, adjf, hnewf);
    }
}

// Round 10
// 181.184 us; speedup vs baseline: 2.8650x; 2.8650x over previous
//
#include <hip/hip_runtime.h>

#define NB   32      // graphs
#define NPER 512     // nodes per graph
#define NN   16384   // total nodes
#define EE   262144  // edges
#define DD   128     // D_IN == D_OUT
#define AS   2048    // total clusters
#define KC   64      // clusters per graph

using short8   = __attribute__((ext_vector_type(8))) short;   // 8 bf16 (4 VGPRs)
using floatx4  = __attribute__((ext_vector_type(4))) float;   // MFMA acc
using ushort4v = __attribute__((ext_vector_type(4))) unsigned short;

typedef __attribute__((address_space(3))) unsigned int lds_u32;
typedef const __attribute__((address_space(1))) unsigned int gbl_u32;

// async 16B global -> LDS (wave-uniform base + lane*16; keep dest linear in tid)
static __device__ __forceinline__ void gload16(const unsigned short* g, unsigned short* l) {
    __builtin_amdgcn_global_load_lds((gbl_u32*)g, (lds_u32*)l, 16, 0, 0);
}

static __device__ __forceinline__ float bits2f(unsigned int u) {
    union { unsigned int i; float f; } z; z.i = u << 16; return z.f;
}
// float -> bf16 bits, round-to-nearest-even
static __device__ __forceinline__ unsigned short f2b(float x) {
    union { float f; unsigned int u; } v; v.f = x;
    unsigned int r = v.u + 0x7fffu + ((v.u >> 16) & 1u);
    return (unsigned short)(r >> 16);
}

// ---- prep: blocks 0-127 cast h -> bundle/hT | 128-1151 edge count | 1152-1695 W transposes ----
union PrepSMem {
    unsigned short fT[128 * 136];
    float tl[32][33];
};
__global__ void prep_kernel(const float* __restrict__ h, unsigned short* __restrict__ bundle,
                            unsigned short* __restrict__ hT, const int* __restrict__ esrc,
                            const int* __restrict__ edst, unsigned int* __restrict__ Acnt,
                            const float* __restrict__ Wf, const float* __restrict__ Wp,
                            unsigned short* __restrict__ WfT, unsigned short* __restrict__ WpT) {
    __shared__ PrepSMem sm;
    int b = blockIdx.x, t = threadIdx.x;
    if (b < 128) {
        int node0 = b * 128;
        int r = t >> 1, hf = t & 1;
        const float4* h4 = reinterpret_cast<const float4*>(h + (size_t)(node0 + r) * 128 + hf * 64);
        unsigned short* bo = bundle + (size_t)(node0 + r) * 256 + hf * 64;
#pragma unroll
        for (int i = 0; i < 16; i++) {
            float4 v = h4[i];
            ushort4v o = { f2b(v.x), f2b(v.y), f2b(v.z), f2b(v.w) };
            *reinterpret_cast<ushort4v*>(bo + 4 * i) = o;
            int c = hf * 64 + 4 * i;
            sm.fT[(c + 0) * 136 + r] = o.x;
            sm.fT[(c + 1) * 136 + r] = o.y;
            sm.fT[(c + 2) * 136 + r] = o.z;
            sm.fT[(c + 3) * 136 + r] = o.w;
        }
        __syncthreads();
        int c = t >> 1, nh = t & 1;
        const uint4* src = reinterpret_cast<const uint4*>(&sm.fT[c * 136 + nh * 64]);
        uint4* dst = reinterpret_cast<uint4*>(hT + (size_t)c * NN + node0 + nh * 64);
#pragma unroll
        for (int i = 0; i < 8; i++) dst[i] = src[i];
    } else if (b < 1152) {
        int e = (b - 128) * 256 + t;
        int d = edst[e], sl = esrc[e] & 511;
        int idx = d * 512 + sl;
        atomicAdd(&Acnt[idx >> 2], 1u << (8 * (idx & 3)));
    } else {
        int tb = b - 1152;                 // 0..543 ; logical grid (68, 8)
        int bx = tb % 68, by = tb / 68;
        int tx = t & 31, ty = t >> 5;      // (32, 8)
        const float* in; unsigned short* out; int C, cb;
        if (bx < DD / 32) { in = Wf; out = WfT; C = DD; cb = bx; }
        else              { in = Wp; out = WpT; C = AS; cb = bx - DD / 32; }
        int c0 = cb * 32, r0 = by * 32;
        for (int i = 0; i < 4; i++)
            sm.tl[ty + 8 * i][tx] = in[(size_t)(r0 + ty + 8 * i) * C + c0 + tx];
        __syncthreads();
        for (int i = 0; i < 4; i++)
            out[(size_t)(c0 + ty + 8 * i) * 256 + r0 + tx] = f2b(sm.tl[tx][ty + 8 * i]);
    }
}

// ---- conv: uint8 counts -> A_adj bf16 [dst][512 src] + invdeg (rowsum, exact) ----
__global__ void conv_kernel(const unsigned int* __restrict__ Acnt,
                            unsigned short* __restrict__ Aadj, float* __restrict__ invdeg) {
    int t = threadIdx.x;
    int row = blockIdx.x * 8 + (t >> 5);
    int u = t & 31;
    uint4 w = reinterpret_cast<const uint4*>(Acnt)[(size_t)row * 32 + u];
    unsigned int wa[4] = { w.x, w.y, w.z, w.w };
    unsigned short out[16];
    float sum = 0.f;
#pragma unroll
    for (int i = 0; i < 4; i++) {
#pragma unroll
        for (int bb = 0; bb < 4; bb++) {
            float fv = (float)((wa[i] >> (8 * bb)) & 0xffu);
            sum += fv;
            out[4 * i + bb] = f2b(fv);
        }
    }
    unsigned int pw[8];
#pragma unroll
    for (int i = 0; i < 8; i++)
        pw[i] = (unsigned int)out[2 * i] | ((unsigned int)out[2 * i + 1] << 16);
    uint4* dst = reinterpret_cast<uint4*>(Aadj + (size_t)row * 512 + u * 16);
    uint4 s0 = { pw[0], pw[1], pw[2], pw[3] }, s1 = { pw[4], pw[5], pw[6], pw[7] };
    dst[0] = s0; dst[1] = s1;
#pragma unroll
    for (int d = 1; d < 32; d <<= 1) sum += __shfl_xor(sum, d, 64);
    if (u == 0) invdeg[row] = 1.0f / fmaxf(sum, 1.0f);
}

// ---- agg_h via MFMA: msg[dst][c] = sum_src A[dst][src] h[src][c]; /deg -> bundle upper ----
__global__ __launch_bounds__(256) void agg_h_mfma_kernel(
    const unsigned short* __restrict__ Aadj, const unsigned short* __restrict__ hT,
    const float* __restrict__ invdeg, unsigned short* __restrict__ bundle) {
    __shared__ alignas(16) unsigned short lA[64 * 512];
    int tid = threadIdx.x, bx = blockIdx.x;
    int r0 = bx * 64, g = bx >> 3;
    int wv = tid >> 6, lane = tid & 63, q = lane >> 4, lm = lane & 15;
    int mw = wv >> 1, nw = wv & 1;
#pragma unroll
    for (int j = 0; j < 16; j++) {
        int u = tid + 256 * j;
        int row = u >> 6, cu = (u & 63) ^ (row & 7);
        gload16(Aadj + (size_t)(r0 + row) * 512 + cu * 8, &lA[u * 8]);
    }
    floatx4 acc[2][4];
#pragma unroll
    for (int mt = 0; mt < 2; mt++)
#pragma unroll
        for (int nt = 0; nt < 4; nt++) acc[mt][nt] = (floatx4)0.f;
    __syncthreads();
    const unsigned short* Bb = hT + (size_t)(64 * nw + lm) * NN + g * 512 + (q << 3);
    short8 bF[2][4];
#pragma unroll
    for (int nt = 0; nt < 4; nt++)
        bF[0][nt] = *reinterpret_cast<const short8*>(Bb + (size_t)16 * nt * NN);
    for (int ki = 0; ki < 16; ki++) {
        if (ki < 15) {
#pragma unroll
            for (int nt = 0; nt < 4; nt++)
                bF[(ki + 1) & 1][nt] =
                    *reinterpret_cast<const short8*>(Bb + (size_t)16 * nt * NN + (ki + 1) * 32);
        }
        short8 aF[2];
        int swz = (4 * ki + q) ^ (lm & 7);
#pragma unroll
        for (int mt = 0; mt < 2; mt++)
            aF[mt] = *reinterpret_cast<const short8*>(&lA[((32 * mw + 16 * mt + lm) * 64 + swz) * 8]);
#pragma unroll
        for (int mt = 0; mt < 2; mt++)
#pragma unroll
            for (int nt = 0; nt < 4; nt++)
                acc[mt][nt] = __builtin_amdgcn_mfma_f32_16x16x32_bf16(aF[mt], bF[ki & 1][nt],
                                                                      acc[mt][nt], 0, 0, 0);
    }
#pragma unroll
    for (int mt = 0; mt < 2; mt++)
#pragma unroll
        for (int r = 0; r < 4; r++) {
            int row = 32 * mw + 16 * mt + 4 * q + r;
            float inv = invdeg[r0 + row];
#pragma unroll
            for (int nt = 0; nt < 4; nt++)
                bundle[(size_t)(r0 + row) * 256 + 128 + 64 * nw + 16 * nt + lm] =
                    f2b(acc[mt][nt][r] * inv);
        }
}

// ---- fused feat (blocks 0-127) + pool (blocks 128-383) ----
union FPSMem {
    struct { unsigned short lA[4096]; unsigned short lB[4096]; float red[256];
             unsigned short fT[17408]; } feat;
    struct { unsigned short lA[16384]; float raw[4352]; float ssq[256]; float rn[64]; } pool;
};
__global__ __launch_bounds__(256) void featpool_kernel(
    const unsigned short* __restrict__ bundle, const unsigned short* __restrict__ WfT,
    const unsigned short* __restrict__ WpT, const float* __restrict__ bfe,
    const float* __restrict__ bp, unsigned short* __restrict__ featT,
    unsigned short* __restrict__ sT) {
    __shared__ FPSMem sm;
    int tid = threadIdx.x, b = blockIdx.x;
    if (b < 128) {
        // ---- feat: GEMM + bias + L2norm + relu -> featT ----
        int r0 = b * 128;
        int wv = tid >> 6, lane = tid & 63;
        int mw = wv >> 1, nw = wv & 1, q = lane >> 4, lm = lane & 15;
        int rowS0 = tid >> 2,         cS0 = (tid & 3) ^ ((rowS0 >> 1) & 3);
        int rowS1 = (tid + 256) >> 2, cS1 = ((tid + 256) & 3) ^ ((rowS1 >> 1) & 3);
        int swz = q ^ ((lm >> 1) & 3);
        floatx4 acc[4][4];
#pragma unroll
        for (int mi = 0; mi < 4; mi++)
#pragma unroll
            for (int ni = 0; ni < 4; ni++) acc[mi][ni] = (floatx4)0.f;
        for (int k0 = 0; k0 < 256; k0 += 32) {
            gload16(bundle + (size_t)(r0 + rowS0) * 256 + k0 + 8 * cS0, &sm.feat.lA[tid * 8]);
            gload16(bundle + (size_t)(r0 + rowS1) * 256 + k0 + 8 * cS1, &sm.feat.lA[(tid + 256) * 8]);
            gload16(WfT + (size_t)rowS0 * 256 + k0 + 8 * cS0, &sm.feat.lB[tid * 8]);
            gload16(WfT + (size_t)rowS1 * 256 + k0 + 8 * cS1, &sm.feat.lB[(tid + 256) * 8]);
            __syncthreads();
            short8 aF[4], bF[4];
#pragma unroll
            for (int mi = 0; mi < 4; mi++)
                aF[mi] = *reinterpret_cast<const short8*>(&sm.feat.lA[((64 * mw + 16 * mi + lm) * 4 + swz) * 8]);
#pragma unroll
            for (int ni = 0; ni < 4; ni++)
                bF[ni] = *reinterpret_cast<const short8*>(&sm.feat.lB[((64 * nw + 16 * ni + lm) * 4 + swz) * 8]);
#pragma unroll
            for (int mi = 0; mi < 4; mi++)
#pragma unroll
                for (int ni = 0; ni < 4; ni++)
                    acc[mi][ni] = __builtin_amdgcn_mfma_f32_16x16x32_bf16(aF[mi], bF[ni], acc[mi][ni], 0, 0, 0);
            __syncthreads();
        }
#pragma unroll
        for (int ni = 0; ni < 4; ni++) {
            float bv = bfe[64 * nw + 16 * ni + lm];
#pragma unroll
            for (int mi = 0; mi < 4; mi++)
#pragma unroll
                for (int r = 0; r < 4; r++) acc[mi][ni][r] += bv;
        }
#pragma unroll
        for (int mi = 0; mi < 4; mi++)
#pragma unroll
            for (int r = 0; r < 4; r++) {
                float p = 0.f;
#pragma unroll
                for (int ni = 0; ni < 4; ni++) p += acc[mi][ni][r] * acc[mi][ni][r];
                p += __shfl_xor(p, 1, 64);
                p += __shfl_xor(p, 2, 64);
                p += __shfl_xor(p, 4, 64);
                p += __shfl_xor(p, 8, 64);
                if (lm == 0) sm.feat.red[nw * 128 + 64 * mw + 16 * mi + 4 * q + r] = p;
            }
        __syncthreads();
#pragma unroll
        for (int mi = 0; mi < 4; mi++) {
            float rrn[4];
#pragma unroll
            for (int r = 0; r < 4; r++) {
                int rl = 64 * mw + 16 * mi + 4 * q + r;
                rrn[r] = 1.0f / fmaxf(sqrtf(sm.feat.red[rl] + sm.feat.red[128 + rl]), 1e-12f);
            }
#pragma unroll
            for (int ni = 0; ni < 4; ni++) {
                int col = 64 * nw + 16 * ni + lm;
                ushort4v pk = { f2b(fmaxf(acc[mi][ni][0] * rrn[0], 0.f)),
                                f2b(fmaxf(acc[mi][ni][1] * rrn[1], 0.f)),
                                f2b(fmaxf(acc[mi][ni][2] * rrn[2], 0.f)),
                                f2b(fmaxf(acc[mi][ni][3] * rrn[3], 0.f)) };
                *reinterpret_cast<ushort4v*>(&sm.feat.fT[col * 136 + 64 * mw + 16 * mi + 4 * q]) = pk;
            }
        }
        __syncthreads();
        {
            int col = tid >> 1, half = tid & 1;
            const uint4* src = reinterpret_cast<const uint4*>(&sm.feat.fT[col * 136 + half * 64]);
            uint4* dst = reinterpret_cast<uint4*>(featT + (size_t)col * NN + r0 + half * 64);
#pragma unroll
            for (int i = 0; i < 8; i++) dst[i] = src[i];
        }
    } else {
        // ---- pool: A-resident GEMM + bias + ssq + norm + softmax -> sT ----
        int bx = b - 128;
        int r0 = bx * 64, g = bx >> 3;
        int wv = tid >> 6, lane = tid & 63, q = lane >> 4, lm = lane & 15;
#pragma unroll
        for (int j = 0; j < 8; j++) {
            int u = tid + 256 * j;
            int row = u >> 5;
            int chunk = (u & 31) ^ (row & 7);
            gload16(bundle + (size_t)(r0 + row) * 256 + chunk * 8, &sm.pool.lA[u * 8]);
        }
        float ssqacc[4][4];
#pragma unroll
        for (int mi = 0; mi < 4; mi++)
#pragma unroll
            for (int r = 0; r < 4; r++) ssqacc[mi][r] = 0.f;
        __syncthreads();
        for (int nc8 = 0; nc8 < 8; nc8++) {
            int nc = 4 * nc8 + wv;
            const unsigned short* Bb = WpT + ((size_t)(nc * 64 + lm) << 8) + (q << 3);
            short8 bF[2][4];
#pragma unroll
            for (int ni = 0; ni < 4; ni++)
                bF[0][ni] = *reinterpret_cast<const short8*>(Bb + (ni << 12));
            floatx4 acc[4][4];
#pragma unroll
            for (int mi = 0; mi < 4; mi++)
#pragma unroll
                for (int ni = 0; ni < 4; ni++) acc[mi][ni] = (floatx4)0.f;
#pragma unroll
            for (int k = 0; k < 8; k++) {
                if (k < 7) {
#pragma unroll
                    for (int ni = 0; ni < 4; ni++)
                        bF[(k + 1) & 1][ni] =
                            *reinterpret_cast<const short8*>(Bb + (ni << 12) + ((k + 1) << 5));
                }
                short8 aF[4];
                int swz = (4 * k + q) ^ (lm & 7);
#pragma unroll
                for (int mi = 0; mi < 4; mi++)
                    aF[mi] = *reinterpret_cast<const short8*>(&sm.pool.lA[((16 * mi + lm) * 32 + swz) * 8]);
#pragma unroll
                for (int mi = 0; mi < 4; mi++)
#pragma unroll
                    for (int ni = 0; ni < 4; ni++)
                        acc[mi][ni] = __builtin_amdgcn_mfma_f32_16x16x32_bf16(aF[mi], bF[k & 1][ni],
                                                                              acc[mi][ni], 0, 0, 0);
            }
            float bv[4];
#pragma unroll
            for (int ni = 0; ni < 4; ni++) bv[ni] = bp[nc * 64 + 16 * ni + lm];
#pragma unroll
            for (int mi = 0; mi < 4; mi++)
#pragma unroll
                for (int r = 0; r < 4; r++) {
                    float p = 0.f;
#pragma unroll
                    for (int ni = 0; ni < 4; ni++) {
                        acc[mi][ni][r] += bv[ni];
                        p += acc[mi][ni][r] * acc[mi][ni][r];
                    }
                    ssqacc[mi][r] += p;
                }
            if (nc == g) {
#pragma unroll
                for (int mi = 0; mi < 4; mi++)
#pragma unroll
                    for (int ni = 0; ni < 4; ni++)
#pragma unroll
                        for (int r = 0; r < 4; r++)
                            sm.pool.raw[(16 * mi + 4 * q + r) * 68 + 16 * ni + lm] = acc[mi][ni][r];
            }
        }
#pragma unroll
        for (int mi = 0; mi < 4; mi++)
#pragma unroll
            for (int r = 0; r < 4; r++) {
                float p = ssqacc[mi][r];
                p += __shfl_xor(p, 1, 64);
                p += __shfl_xor(p, 2, 64);
                p += __shfl_xor(p, 4, 64);
                p += __shfl_xor(p, 8, 64);
                if (lm == 0) sm.pool.ssq[wv * 64 + 16 * mi + 4 * q + r] = p;
            }
        __syncthreads();
        if (tid < 64)
            sm.pool.rn[tid] = 1.0f / fmaxf(sqrtf(sm.pool.ssq[tid] + sm.pool.ssq[64 + tid] +
                                           sm.pool.ssq[128 + tid] + sm.pool.ssq[192 + tid]), 1e-12f);
        __syncthreads();
        {
            int row = tid >> 2, j = tid & 3;
            int nloc = ((bx & 7) << 6) + row;
            float rn = sm.pool.rn[row];
            float v[16];
            float mx = -1e30f;
#pragma unroll
            for (int c4 = 0; c4 < 4; c4++) {
                float4 rv = *reinterpret_cast<const float4*>(&sm.pool.raw[row * 68 + 16 * j + 4 * c4]);
                v[4 * c4 + 0] = fmaxf(rv.x * rn, 0.f);
                v[4 * c4 + 1] = fmaxf(rv.y * rn, 0.f);
                v[4 * c4 + 2] = fmaxf(rv.z * rn, 0.f);
                v[4 * c4 + 3] = fmaxf(rv.w * rn, 0.f);
            }
#pragma unroll
            for (int c = 0; c < 16; c++) mx = fmaxf(mx, v[c]);
            mx = fmaxf(mx, __shfl_xor(mx, 1, 64));
            mx = fmaxf(mx, __shfl_xor(mx, 2, 64));
            float z = 0.f;
#pragma unroll
            for (int c = 0; c < 16; c++) { v[c] = __expf(v[c] - mx); z += v[c]; }
            z += __shfl_xor(z, 1, 64);
            z += __shfl_xor(z, 2, 64);
            float iz = 1.0f / z;
#pragma unroll
            for (int c4 = 0; c4 < 4; c4++) {
                size_t tb = (size_t)(g * KC + 16 * j + 4 * c4) * NPER + nloc;
                sT[tb] = f2b(v[4 * c4 + 0] * iz);
                sT[tb + NPER] = f2b(v[4 * c4 + 1] * iz);
                sT[tb + 2 * NPER] = f2b(v[4 * c4 + 2] * iz);
                sT[tb + 3 * NPER] = f2b(v[4 * c4 + 3] * iz);
            }
        }
    }
}

// ---- a_s via MFMA: asT[cl][dst] = sum_src sT[cl][src] * A[dst][src] ----
__global__ __launch_bounds__(256) void as_mfma_kernel(
    const unsigned short* __restrict__ sT, const unsigned short* __restrict__ Aadj,
    unsigned short* __restrict__ asT) {
    __shared__ alignas(16) unsigned short lS[64 * 512];
    int tid = threadIdx.x, bx = blockIdx.x;
    int g = bx >> 1, half = bx & 1;
    int wv = tid >> 6, lane = tid & 63, q = lane >> 4, lm = lane & 15;
#pragma unroll
    for (int j = 0; j < 16; j++) {
        int u = tid + 256 * j;
        int row = u >> 6, cu = (u & 63) ^ (row & 7);
        gload16(sT + (size_t)(g * KC + row) * NPER + cu * 8, &lS[u * 8]);
    }
    floatx4 acc[4][4];
#pragma unroll
    for (int mi = 0; mi < 4; mi++)
#pragma unroll
        for (int nt = 0; nt < 4; nt++) acc[mi][nt] = (floatx4)0.f;
    __syncthreads();
    int dbase = half * 256 + wv * 64;
    const unsigned short* Bb = Aadj + (size_t)(g * 512 + dbase + lm) * 512 + (q << 3);
    short8 bF[2][4];
#pragma unroll
    for (int nt = 0; nt < 4; nt++)
        bF[0][nt] = *reinterpret_cast<const short8*>(Bb + (size_t)16 * nt * 512);
    for (int ki = 0; ki < 16; ki++) {
        if (ki < 15) {
#pragma unroll
            for (int nt = 0; nt < 4; nt++)
                bF[(ki + 1) & 1][nt] =
                    *reinterpret_cast<const short8*>(Bb + (size_t)16 * nt * 512 + (ki + 1) * 32);
        }
        short8 aF[4];
        int swz = (4 * ki + q) ^ (lm & 7);
#pragma unroll
        for (int mi = 0; mi < 4; mi++)
            aF[mi] = *reinterpret_cast<const short8*>(&lS[((16 * mi + lm) * 64 + swz) * 8]);
#pragma unroll
        for (int mi = 0; mi < 4; mi++)
#pragma unroll
            for (int nt = 0; nt < 4; nt++)
                acc[mi][nt] = __builtin_amdgcn_mfma_f32_16x16x32_bf16(aF[mi], bF[ki & 1][nt],
                                                                      acc[mi][nt], 0, 0, 0);
    }
#pragma unroll
    for (int mi = 0; mi < 4; mi++)
#pragma unroll
        for (int r = 0; r < 4; r++) {
            int row = 16 * mi + 4 * q + r;
#pragma unroll
            for (int nt = 0; nt < 4; nt++)
                asT[(size_t)(g * KC + row) * NPER + dbase + 16 * nt + lm] = f2b(acc[mi][nt][r]);
        }
}

// ---- hnew+adj v2: blocks 0-31 compute graph g (full K in regs, plain stores);
// ---- blocks 32-255 zero the off-diagonal adj strips (disjoint regions) ----
__global__ __launch_bounds__(256) void hnew_adj2_kernel(
    const unsigned short* __restrict__ sT, const unsigned short* __restrict__ featT,
    const unsigned short* __restrict__ asT, float* __restrict__ adjf,
    float* __restrict__ hnewf) {
    __shared__ alignas(16) unsigned short lS[1024 * 8];   // 64 cl x 128 nodes
    __shared__ alignas(16) unsigned short lF[2048 * 8];   // 128 cols x 128 nodes
    __shared__ alignas(16) unsigned short lAS[1024 * 8];  // 64 cl x 128 nodes
    int tid = threadIdx.x, b = blockIdx.x;
    if (b >= 32) {
        // zero off-diagonal adj: rows grid-strided over 224 blocks
        uint4 z = { 0u, 0u, 0u, 0u };
        for (int row = b - 32; row < AS; row += 224) {
            int g = row >> 6;
            uint4* out = reinterpret_cast<uint4*>(adjf + (size_t)row * AS);
            for (int i = tid; i < 512; i += 256)
                if (i < g * 16 || i >= g * 16 + 16) out[i] = z;
        }
        return;
    }
    int g = b;
    int wv = tid >> 6, lane = tid & 63, q = lane >> 4, lm = lane & 15;
    bool isH = (wv < 2);
    floatx4 accH[4][4];
    floatx4 accA[4][2];
#pragma unroll
    for (int mi = 0; mi < 4; mi++) {
#pragma unroll
        for (int ni = 0; ni < 4; ni++) accH[mi][ni] = (floatx4)0.f;
#pragma unroll
        for (int ni = 0; ni < 2; ni++) accA[mi][ni] = (floatx4)0.f;
    }
    for (int ks = 0; ks < 4; ks++) {
#pragma unroll
        for (int j = 0; j < 4; j++) {
            int u = tid + 256 * j;
            int row = u >> 4, cu = (u & 15) ^ (row & 15);
            gload16(sT + (size_t)(g * KC + row) * NPER + ks * 128 + cu * 8, &lS[u * 8]);
        }
#pragma unroll
        for (int j = 0; j < 8; j++) {
            int u = tid + 256 * j;
            int row = u >> 4, cu = (u & 15) ^ (row & 15);
            gload16(featT + (size_t)row * NN + g * NPER + ks * 128 + cu * 8, &lF[u * 8]);
        }
#pragma unroll
        for (int j = 0; j < 4; j++) {
            int u = tid + 256 * j;
            int row = u >> 4, cu = (u & 15) ^ (row & 15);
            gload16(asT + (size_t)(g * KC + row) * NPER + ks * 128 + cu * 8, &lAS[u * 8]);
        }
        __syncthreads();
#pragma unroll
        for (int kk = 0; kk < 4; kk++) {
            short8 aF[4];
#pragma unroll
            for (int mi = 0; mi < 4; mi++)
                aF[mi] = *reinterpret_cast<const short8*>(
                    &lS[((16 * mi + lm) * 16 + ((4 * kk + q) ^ lm)) * 8]);
            if (isH) {
                short8 bF[4];
#pragma unroll
                for (int ni = 0; ni < 4; ni++)
                    bF[ni] = *reinterpret_cast<const short8*>(
                        &lF[((64 * wv + 16 * ni + lm) * 16 + ((4 * kk + q) ^ lm)) * 8]);
#pragma unroll
                for (int mi = 0; mi < 4; mi++)
#pragma unroll
                    for (int ni = 0; ni < 4; ni++)
                        accH[mi][ni] = __builtin_amdgcn_mfma_f32_16x16x32_bf16(aF[mi], bF[ni],
                                                                               accH[mi][ni], 0, 0, 0);
            } else {
                short8 bF[2];
#pragma unroll
                for (int ni = 0; ni < 2; ni++)
                    bF[ni] = *reinterpret_cast<const short8*>(
                        &lAS[((32 * (wv - 2) + 16 * ni + lm) * 16 + ((4 * kk + q) ^ lm)) * 8]);
#pragma unroll
                for (int mi = 0; mi < 4; mi++)
#pragma unroll
                    for (int ni = 0; ni < 2; ni++)
                        accA[mi][ni] = __builtin_amdgcn_mfma_f32_16x16x32_bf16(aF[mi], bF[ni],
                                                                               accA[mi][ni], 0, 0, 0);
            }
        }
        __syncthreads();
    }
    if (isH) {
#pragma unroll
        for (int mi = 0; mi < 4; mi++)
#pragma unroll
            for (int ni = 0; ni < 4; ni++)
#pragma unroll
                for (int r = 0; r < 4; r++)
                    hnewf[(size_t)(g * KC + 16 * mi + 4 * q + r) * DD +
                          64 * wv + 16 * ni + lm] = accH[mi][ni][r];
    } else {
#pragma unroll
        for (int mi = 0; mi < 4; mi++)
#pragma unroll
            for (int ni = 0; ni < 2; ni++)
#pragma unroll
                for (int r = 0; r < 4; r++)
                    adjf[(size_t)(g * KC + 16 * mi + 4 * q + r) * AS +
                         g * KC + 32 * (wv - 2) + 16 * ni + lm] = accA[mi][ni][r];
    }
}

extern "C" void kernel_launch(void* const* d_in, const int* in_sizes, int n_in,
                              void* d_out, int out_size, void* d_ws, size_t ws_size,
                              hipStream_t stream) {
    const float* h   = (const float*)d_in[0];
    const float* Wf  = (const float*)d_in[1];
    const float* bfe = (const float*)d_in[2];
    const float* Wp  = (const float*)d_in[3];
    const float* bp  = (const float*)d_in[4];
    const int* esrc  = (const int*)d_in[5];
    const int* edst  = (const int*)d_in[6];

    float* adjf  = (float*)d_out;
    float* hnewf = adjf + (size_t)AS * AS;

    unsigned short* bundle = (unsigned short*)d_ws;        // NN*256 bf16
    unsigned short* WfT   = bundle + (size_t)NN * 256;     // 128*256
    unsigned short* WpT   = WfT + 128 * 256;               // 2048*256
    unsigned short* sT    = WpT + (size_t)AS * 256;        // NN*KC   [g*64+cl][node]
    unsigned short* asT   = sT + (size_t)NN * KC;          // NN*KC
    unsigned short* featT = asT + (size_t)NN * KC;         // DD*NN
    unsigned short* hT    = featT + (size_t)DD * NN;       // DD*NN
    unsigned short* Aadj  = hT + (size_t)DD * NN;          // NN*512 bf16 (16 MB)
    float* invdeg = (float*)(Aadj + (size_t)NN * 512);     // NN
    unsigned int* Acnt = (unsigned int*)(invdeg + NN);     // NN*512 bytes (8.4 MB)

    hipMemsetAsync(Acnt, 0, (size_t)NN * 512, stream);

    prep_kernel<<<128 + EE / 256 + 544, 256, 0, stream>>>(h, bundle, hT, esrc, edst, Acnt,
                                                          Wf, Wp, WfT, WpT);
    conv_kernel<<<NN / 8, 256, 0, stream>>>(Acnt, Aadj, invdeg);
    agg_h_mfma_kernel<<<NN / 64, 256, 0, stream>>>(Aadj, hT, invdeg, bundle);
    featpool_kernel<<<384, 256, 0, stream>>>(bundle, WfT, WpT, bfe, bp, featT, sT);
    as_mfma_kernel<<<NB * 2, 256, 0, stream>>>(sT, Aadj, asT);
    hnew_adj2_kernel<<<256, 256, 0, stream>>>(sT, featT, asT, adjf, hnewf);
}

// Round 11
// 174.139 us; speedup vs baseline: 2.9809x; 1.0405x over previous
//
#include <hip/hip_runtime.h>

#define NB   32      // graphs
#define NPER 512     // nodes per graph
#define NN   16384   // total nodes
#define EE   262144  // edges
#define DD   128     // D_IN == D_OUT
#define AS   2048    // total clusters
#define KC   64      // clusters per graph

using short8   = __attribute__((ext_vector_type(8))) short;   // 8 bf16 (4 VGPRs)
using floatx4  = __attribute__((ext_vector_type(4))) float;   // MFMA acc
using ushort4v = __attribute__((ext_vector_type(4))) unsigned short;

typedef __attribute__((address_space(3))) unsigned int lds_u32;
typedef const __attribute__((address_space(1))) unsigned int gbl_u32;

// async 16B global -> LDS (wave-uniform base + lane*16; keep dest linear in tid)
static __device__ __forceinline__ void gload16(const unsigned short* g, unsigned short* l) {
    __builtin_amdgcn_global_load_lds((gbl_u32*)g, (lds_u32*)l, 16, 0, 0);
}

static __device__ __forceinline__ float bits2f(unsigned int u) {
    union { unsigned int i; float f; } z; z.i = u << 16; return z.f;
}
// float -> bf16 bits, round-to-nearest-even
static __device__ __forceinline__ unsigned short f2b(float x) {
    union { float f; unsigned int u; } v; v.f = x;
    unsigned int r = v.u + 0x7fffu + ((v.u >> 16) & 1u);
    return (unsigned short)(r >> 16);
}

// ---- prep: 0-127 cast h -> bundle/hT | 128-1151 edge count | 1152-1695 W transposes
// ----       | 1696-2207 cast Wp -> Wpb (row-major bf16) ----
union PrepSMem {
    unsigned short fT[128 * 136];
    float tl[32][33];
};
__global__ void prep_kernel(const float* __restrict__ h, unsigned short* __restrict__ bundle,
                            unsigned short* __restrict__ hT, const int* __restrict__ esrc,
                            const int* __restrict__ edst, unsigned int* __restrict__ Acnt,
                            const float* __restrict__ Wf, const float* __restrict__ Wp,
                            unsigned short* __restrict__ WfT, unsigned short* __restrict__ WpT,
                            unsigned short* __restrict__ Wpb) {
    __shared__ PrepSMem sm;
    int b = blockIdx.x, t = threadIdx.x;
    if (b < 128) {
        int node0 = b * 128;
        int r = t >> 1, hf = t & 1;
        const float4* h4 = reinterpret_cast<const float4*>(h + (size_t)(node0 + r) * 128 + hf * 64);
        unsigned short* bo = bundle + (size_t)(node0 + r) * 256 + hf * 64;
#pragma unroll
        for (int i = 0; i < 16; i++) {
            float4 v = h4[i];
            ushort4v o = { f2b(v.x), f2b(v.y), f2b(v.z), f2b(v.w) };
            *reinterpret_cast<ushort4v*>(bo + 4 * i) = o;
            int c = hf * 64 + 4 * i;
            sm.fT[(c + 0) * 136 + r] = o.x;
            sm.fT[(c + 1) * 136 + r] = o.y;
            sm.fT[(c + 2) * 136 + r] = o.z;
            sm.fT[(c + 3) * 136 + r] = o.w;
        }
        __syncthreads();
        int c = t >> 1, nh = t & 1;
        const uint4* src = reinterpret_cast<const uint4*>(&sm.fT[c * 136 + nh * 64]);
        uint4* dst = reinterpret_cast<uint4*>(hT + (size_t)c * NN + node0 + nh * 64);
#pragma unroll
        for (int i = 0; i < 8; i++) dst[i] = src[i];
    } else if (b < 1152) {
        int e = (b - 128) * 256 + t;
        int d = edst[e], sl = esrc[e] & 511;
        int idx = d * 512 + sl;
        atomicAdd(&Acnt[idx >> 2], 1u << (8 * (idx & 3)));
    } else if (b < 1696) {
        int tb = b - 1152;                 // 0..543 ; logical grid (68, 8)
        int bx = tb % 68, by = tb / 68;
        int tx = t & 31, ty = t >> 5;      // (32, 8)
        const float* in; unsigned short* out; int C, cb;
        if (bx < DD / 32) { in = Wf; out = WfT; C = DD; cb = bx; }
        else              { in = Wp; out = WpT; C = AS; cb = bx - DD / 32; }
        int c0 = cb * 32, r0 = by * 32;
        for (int i = 0; i < 4; i++)
            sm.tl[ty + 8 * i][tx] = in[(size_t)(r0 + ty + 8 * i) * C + c0 + tx];
        __syncthreads();
        for (int i = 0; i < 4; i++)
            out[(size_t)(c0 + ty + 8 * i) * 256 + r0 + tx] = f2b(sm.tl[tx][ty + 8 * i]);
    } else {
        int gid = (b - 1696) * 256 + t;    // one float4 each; 512*256*4 = 256*2048
        float4 v = reinterpret_cast<const float4*>(Wp)[gid];
        ushort4v o = { f2b(v.x), f2b(v.y), f2b(v.z), f2b(v.w) };
        *reinterpret_cast<ushort4v*>(&Wpb[(size_t)gid * 4]) = o;
    }
}

// ---- conv (0-2047): uint8 counts -> Aadj bf16 + invdeg  |  ggemm (2048-2063):
// ---- G = Wp Wp^T (K-split, fp32 atomics) + u = Wp b + c = ||b||^2 ----
__global__ __launch_bounds__(256) void conv_kernel(
    const unsigned int* __restrict__ Acnt, unsigned short* __restrict__ Aadj,
    float* __restrict__ invdeg, const unsigned short* __restrict__ Wpb,
    const float* __restrict__ Wp, const float* __restrict__ bp,
    float* __restrict__ Gf, float* __restrict__ uF, float* __restrict__ cF) {
    __shared__ alignas(16) unsigned short glA[4096];
    __shared__ alignas(16) unsigned short glB[4096];
    __shared__ float gcred[4];
    int t = threadIdx.x, b = blockIdx.x;
    if (b < 2048) {
        int row = b * 8 + (t >> 5);
        int u = t & 31;
        uint4 w = reinterpret_cast<const uint4*>(Acnt)[(size_t)row * 32 + u];
        unsigned int wa[4] = { w.x, w.y, w.z, w.w };
        unsigned short out[16];
        float sum = 0.f;
#pragma unroll
        for (int i = 0; i < 4; i++) {
#pragma unroll
            for (int bb = 0; bb < 4; bb++) {
                float fv = (float)((wa[i] >> (8 * bb)) & 0xffu);
                sum += fv;
                out[4 * i + bb] = f2b(fv);
            }
        }
        unsigned int pw[8];
#pragma unroll
        for (int i = 0; i < 8; i++)
            pw[i] = (unsigned int)out[2 * i] | ((unsigned int)out[2 * i + 1] << 16);
        uint4* dst = reinterpret_cast<uint4*>(Aadj + (size_t)row * 512 + u * 16);
        uint4 s0 = { pw[0], pw[1], pw[2], pw[3] }, s1 = { pw[4], pw[5], pw[6], pw[7] };
        dst[0] = s0; dst[1] = s1;
#pragma unroll
        for (int d = 1; d < 32; d <<= 1) sum += __shfl_xor(sum, d, 64);
        if (u == 0) invdeg[row] = 1.0f / fmaxf(sum, 1.0f);
        return;
    }
    // ggemm
    int b2 = b - 2048;
    int ks = b2 >> 2, ti = (b2 >> 1) & 1, tj = b2 & 1;
    int wv = t >> 6, lane = t & 63;
    int mw = wv >> 1, nw = wv & 1, q = lane >> 4, lm = lane & 15;
    int rowS0 = t >> 2,         cS0 = (t & 3) ^ ((rowS0 >> 1) & 3);
    int rowS1 = (t + 256) >> 2, cS1 = ((t + 256) & 3) ^ ((rowS1 >> 1) & 3);
    int swz = q ^ ((lm >> 1) & 3);
    floatx4 acc[4][4];
#pragma unroll
    for (int mi = 0; mi < 4; mi++)
#pragma unroll
        for (int ni = 0; ni < 4; ni++) acc[mi][ni] = (floatx4)0.f;
    for (int ki = 0; ki < 16; ki++) {
        int k0 = ks * 512 + ki * 32;
        gload16(Wpb + (size_t)(ti * 128 + rowS0) * 2048 + k0 + 8 * cS0, &glA[t * 8]);
        gload16(Wpb + (size_t)(ti * 128 + rowS1) * 2048 + k0 + 8 * cS1, &glA[(t + 256) * 8]);
        gload16(Wpb + (size_t)(tj * 128 + rowS0) * 2048 + k0 + 8 * cS0, &glB[t * 8]);
        gload16(Wpb + (size_t)(tj * 128 + rowS1) * 2048 + k0 + 8 * cS1, &glB[(t + 256) * 8]);
        __syncthreads();
        short8 aF[4], bF[4];
#pragma unroll
        for (int mi = 0; mi < 4; mi++)
            aF[mi] = *reinterpret_cast<const short8*>(&glA[((64 * mw + 16 * mi + lm) * 4 + swz) * 8]);
#pragma unroll
        for (int ni = 0; ni < 4; ni++)
            bF[ni] = *reinterpret_cast<const short8*>(&glB[((64 * nw + 16 * ni + lm) * 4 + swz) * 8]);
#pragma unroll
        for (int mi = 0; mi < 4; mi++)
#pragma unroll
            for (int ni = 0; ni < 4; ni++)
                acc[mi][ni] = __builtin_amdgcn_mfma_f32_16x16x32_bf16(aF[mi], bF[ni], acc[mi][ni], 0, 0, 0);
        __syncthreads();
    }
#pragma unroll
    for (int mi = 0; mi < 4; mi++)
#pragma unroll
        for (int ni = 0; ni < 4; ni++)
#pragma unroll
            for (int r = 0; r < 4; r++)
                atomicAdd(&Gf[(size_t)(ti * 128 + 64 * mw + 16 * mi + 4 * q + r) * 256 +
                              tj * 128 + 64 * nw + 16 * ni + lm], acc[mi][ni][r]);
    if (tj == 0) {
        int row = t >> 1, jh = t & 1;
        const float* wr = Wp + (size_t)(ti * 128 + row) * 2048 + ks * 512 + jh * 256;
        const float* br = bp + ks * 512 + jh * 256;
        float s = 0.f;
        for (int j = 0; j < 256; j++) s += wr[j] * br[j];
        atomicAdd(&uF[ti * 128 + row], s);
    }
    if (b2 == 0) {
        float s = 0.f;
        for (int j = t; j < 2048; j += 256) { float v = bp[j]; s += v * v; }
#pragma unroll
        for (int d = 1; d < 64; d <<= 1) s += __shfl_xor(s, d, 64);
        if (lane == 0) gcred[wv] = s;
        __syncthreads();
        if (t == 0) atomicAdd(cF, gcred[0] + gcred[1] + gcred[2] + gcred[3]);
    }
}

// ---- agg_h (0-255) via MFMA -> bundle upper  |  gconv (256-259): Gf fp32 -> Gb bf16 ----
__global__ __launch_bounds__(256) void agg_h_mfma_kernel(
    const unsigned short* __restrict__ Aadj, const unsigned short* __restrict__ hT,
    const float* __restrict__ invdeg, unsigned short* __restrict__ bundle,
    const float* __restrict__ Gf, unsigned short* __restrict__ Gb) {
    __shared__ alignas(16) unsigned short lA[64 * 512];
    int tid = threadIdx.x, bx = blockIdx.x;
    if (bx >= 256) {
        int base = (bx - 256) * 16384;
        for (int i = 0; i < 16; i++) {
            int idx = base + i * 1024 + tid * 4;
            float4 v = *reinterpret_cast<const float4*>(Gf + idx);
            ushort4v o = { f2b(v.x), f2b(v.y), f2b(v.z), f2b(v.w) };
            *reinterpret_cast<ushort4v*>(&Gb[idx]) = o;
        }
        return;
    }
    int r0 = bx * 64, g = bx >> 3;
    int wv = tid >> 6, lane = tid & 63, q = lane >> 4, lm = lane & 15;
    int mw = wv >> 1, nw = wv & 1;
#pragma unroll
    for (int j = 0; j < 16; j++) {
        int u = tid + 256 * j;
        int row = u >> 6, cu = (u & 63) ^ (row & 7);
        gload16(Aadj + (size_t)(r0 + row) * 512 + cu * 8, &lA[u * 8]);
    }
    floatx4 acc[2][4];
#pragma unroll
    for (int mt = 0; mt < 2; mt++)
#pragma unroll
        for (int nt = 0; nt < 4; nt++) acc[mt][nt] = (floatx4)0.f;
    __syncthreads();
    const unsigned short* Bb = hT + (size_t)(64 * nw + lm) * NN + g * 512 + (q << 3);
    short8 bF[2][4];
#pragma unroll
    for (int nt = 0; nt < 4; nt++)
        bF[0][nt] = *reinterpret_cast<const short8*>(Bb + (size_t)16 * nt * NN);
    for (int ki = 0; ki < 16; ki++) {
        if (ki < 15) {
#pragma unroll
            for (int nt = 0; nt < 4; nt++)
                bF[(ki + 1) & 1][nt] =
                    *reinterpret_cast<const short8*>(Bb + (size_t)16 * nt * NN + (ki + 1) * 32);
        }
        short8 aF[2];
        int swz = (4 * ki + q) ^ (lm & 7);
#pragma unroll
        for (int mt = 0; mt < 2; mt++)
            aF[mt] = *reinterpret_cast<const short8*>(&lA[((32 * mw + 16 * mt + lm) * 64 + swz) * 8]);
#pragma unroll
        for (int mt = 0; mt < 2; mt++)
#pragma unroll
            for (int nt = 0; nt < 4; nt++)
                acc[mt][nt] = __builtin_amdgcn_mfma_f32_16x16x32_bf16(aF[mt], bF[ki & 1][nt],
                                                                      acc[mt][nt], 0, 0, 0);
    }
#pragma unroll
    for (int mt = 0; mt < 2; mt++)
#pragma unroll
        for (int r = 0; r < 4; r++) {
            int row = 32 * mw + 16 * mt + 4 * q + r;
            float inv = invdeg[r0 + row];
#pragma unroll
            for (int nt = 0; nt < 4; nt++)
                bundle[(size_t)(r0 + row) * 256 + 128 + 64 * nw + 16 * nt + lm] =
                    f2b(acc[mt][nt][r] * inv);
        }
}

// ---- fused feat (blocks 0-127) + pool via Gram (blocks 128-383) ----
union FPSMem {
    struct { unsigned short lA[4096]; unsigned short lB[4096]; float red[256];
             unsigned short fT2[8704]; } feat;                  // ~34.6 KB
    struct { unsigned short lA[16384]; float raw[4352]; float ssq[256]; float rn[64];
             float uL[256]; } pool;                             // ~51.3 KB
};
__global__ __launch_bounds__(256) void featpool_kernel(
    const unsigned short* __restrict__ bundle, const unsigned short* __restrict__ WfT,
    const unsigned short* __restrict__ WpT, const unsigned short* __restrict__ Gb,
    const float* __restrict__ bfe, const float* __restrict__ bp,
    const float* __restrict__ uF, const float* __restrict__ cF,
    unsigned short* __restrict__ featT, unsigned short* __restrict__ sT) {
    __shared__ FPSMem sm;
    int tid = threadIdx.x, b = blockIdx.x;
    if (b < 128) {
        // ---- feat: GEMM + bias + L2norm + relu -> featT (2-round LDS transpose) ----
        int r0 = b * 128;
        int wv = tid >> 6, lane = tid & 63;
        int mw = wv >> 1, nw = wv & 1, q = lane >> 4, lm = lane & 15;
        int rowS0 = tid >> 2,         cS0 = (tid & 3) ^ ((rowS0 >> 1) & 3);
        int rowS1 = (tid + 256) >> 2, cS1 = ((tid + 256) & 3) ^ ((rowS1 >> 1) & 3);
        int swz = q ^ ((lm >> 1) & 3);
        floatx4 acc[4][4];
#pragma unroll
        for (int mi = 0; mi < 4; mi++)
#pragma unroll
            for (int ni = 0; ni < 4; ni++) acc[mi][ni] = (floatx4)0.f;
        for (int k0 = 0; k0 < 256; k0 += 32) {
            gload16(bundle + (size_t)(r0 + rowS0) * 256 + k0 + 8 * cS0, &sm.feat.lA[tid * 8]);
            gload16(bundle + (size_t)(r0 + rowS1) * 256 + k0 + 8 * cS1, &sm.feat.lA[(tid + 256) * 8]);
            gload16(WfT + (size_t)rowS0 * 256 + k0 + 8 * cS0, &sm.feat.lB[tid * 8]);
            gload16(WfT + (size_t)rowS1 * 256 + k0 + 8 * cS1, &sm.feat.lB[(tid + 256) * 8]);
            __syncthreads();
            short8 aF[4], bF[4];
#pragma unroll
            for (int mi = 0; mi < 4; mi++)
                aF[mi] = *reinterpret_cast<const short8*>(&sm.feat.lA[((64 * mw + 16 * mi + lm) * 4 + swz) * 8]);
#pragma unroll
            for (int ni = 0; ni < 4; ni++)
                bF[ni] = *reinterpret_cast<const short8*>(&sm.feat.lB[((64 * nw + 16 * ni + lm) * 4 + swz) * 8]);
#pragma unroll
            for (int mi = 0; mi < 4; mi++)
#pragma unroll
                for (int ni = 0; ni < 4; ni++)
                    acc[mi][ni] = __builtin_amdgcn_mfma_f32_16x16x32_bf16(aF[mi], bF[ni], acc[mi][ni], 0, 0, 0);
            __syncthreads();
        }
#pragma unroll
        for (int ni = 0; ni < 4; ni++) {
            float bv = bfe[64 * nw + 16 * ni + lm];
#pragma unroll
            for (int mi = 0; mi < 4; mi++)
#pragma unroll
                for (int r = 0; r < 4; r++) acc[mi][ni][r] += bv;
        }
#pragma unroll
        for (int mi = 0; mi < 4; mi++)
#pragma unroll
            for (int r = 0; r < 4; r++) {
                float p = 0.f;
#pragma unroll
                for (int ni = 0; ni < 4; ni++) p += acc[mi][ni][r] * acc[mi][ni][r];
                p += __shfl_xor(p, 1, 64);
                p += __shfl_xor(p, 2, 64);
                p += __shfl_xor(p, 4, 64);
                p += __shfl_xor(p, 8, 64);
                if (lm == 0) sm.feat.red[nw * 128 + 64 * mw + 16 * mi + 4 * q + r] = p;
            }
        __syncthreads();
        for (int rd = 0; rd < 2; rd++) {
            if (nw == rd) {
#pragma unroll
                for (int mi = 0; mi < 4; mi++) {
                    float rrn[4];
#pragma unroll
                    for (int r = 0; r < 4; r++) {
                        int rl = 64 * mw + 16 * mi + 4 * q + r;
                        rrn[r] = 1.0f / fmaxf(sqrtf(sm.feat.red[rl] + sm.feat.red[128 + rl]), 1e-12f);
                    }
#pragma unroll
                    for (int ni = 0; ni < 4; ni++) {
                        int col_loc = 16 * ni + lm;
                        ushort4v pk = { f2b(fmaxf(acc[mi][ni][0] * rrn[0], 0.f)),
                                        f2b(fmaxf(acc[mi][ni][1] * rrn[1], 0.f)),
                                        f2b(fmaxf(acc[mi][ni][2] * rrn[2], 0.f)),
                                        f2b(fmaxf(acc[mi][ni][3] * rrn[3], 0.f)) };
                        *reinterpret_cast<ushort4v*>(&sm.feat.fT2[col_loc * 136 + 64 * mw + 16 * mi + 4 * q]) = pk;
                    }
                }
            }
            __syncthreads();
#pragma unroll
            for (int i = 0; i < 4; i++) {
                int idx = tid + 256 * i;
                int cl = idx >> 4, pos = idx & 15;
                uint4 v = *reinterpret_cast<const uint4*>(&sm.feat.fT2[cl * 136 + pos * 8]);
                *reinterpret_cast<uint4*>(featT + (size_t)(64 * rd + cl) * NN + r0 + pos * 8) = v;
            }
            __syncthreads();
        }
    } else {
        // ---- pool via Gram: ssq = xGx + 2u.x + c; in-graph 64 cols; softmax -> sT ----
        int bx = b - 128;
        int r0 = bx * 64, g = bx >> 3;
        int wv = tid >> 6, lane = tid & 63, q = lane >> 4, lm = lane & 15;
#pragma unroll
        for (int j = 0; j < 8; j++) {
            int u = tid + 256 * j;
            int row = u >> 5;
            int chunk = (u & 31) ^ (row & 7);
            gload16(bundle + (size_t)(r0 + row) * 256 + chunk * 8, &sm.pool.lA[u * 8]);
        }
        sm.pool.uL[tid] = uF[tid];
        __syncthreads();
        // phase A: Y = X G (this wave's 64 cols = rows 64wv.. of Gb)
        {
            const unsigned short* Bb = Gb + ((size_t)(wv * 64 + lm) << 8) + (q << 3);
            short8 bF[2][4];
#pragma unroll
            for (int ni = 0; ni < 4; ni++)
                bF[0][ni] = *reinterpret_cast<const short8*>(Bb + (ni << 12));
            floatx4 acc[4][4];
#pragma unroll
            for (int mi = 0; mi < 4; mi++)
#pragma unroll
                for (int ni = 0; ni < 4; ni++) acc[mi][ni] = (floatx4)0.f;
#pragma unroll
            for (int k = 0; k < 8; k++) {
                if (k < 7) {
#pragma unroll
                    for (int ni = 0; ni < 4; ni++)
                        bF[(k + 1) & 1][ni] =
                            *reinterpret_cast<const short8*>(Bb + (ni << 12) + ((k + 1) << 5));
                }
                short8 aF[4];
                int swz = (4 * k + q) ^ (lm & 7);
#pragma unroll
                for (int mi = 0; mi < 4; mi++)
                    aF[mi] = *reinterpret_cast<const short8*>(&sm.pool.lA[((16 * mi + lm) * 32 + swz) * 8]);
#pragma unroll
                for (int mi = 0; mi < 4; mi++)
#pragma unroll
                    for (int ni = 0; ni < 4; ni++)
                        acc[mi][ni] = __builtin_amdgcn_mfma_f32_16x16x32_bf16(aF[mi], bF[k & 1][ni],
                                                                              acc[mi][ni], 0, 0, 0);
            }
            // ssq partial: (Y + 2u) . X over this lane's cols
            float uc[4];
#pragma unroll
            for (int ni = 0; ni < 4; ni++) uc[ni] = sm.pool.uL[64 * wv + 16 * ni + lm];
#pragma unroll
            for (int mi = 0; mi < 4; mi++)
#pragma unroll
                for (int r = 0; r < 4; r++) {
                    int row = 16 * mi + 4 * q + r;
                    float p = 0.f;
#pragma unroll
                    for (int ni = 0; ni < 4; ni++) {
                        int col = 64 * wv + 16 * ni + lm;
                        int cu = (col >> 3) ^ (row & 7);
                        float xv = bits2f((unsigned int)sm.pool.lA[(row * 32 + cu) * 8 + (col & 7)]);
                        p += (acc[mi][ni][r] + 2.f * uc[ni]) * xv;
                    }
                    p += __shfl_xor(p, 1, 64);
                    p += __shfl_xor(p, 2, 64);
                    p += __shfl_xor(p, 4, 64);
                    p += __shfl_xor(p, 8, 64);
                    if (lm == 0) sm.pool.ssq[wv * 64 + row] = p;
                }
        }
        // phase B: in-graph col 16wv+lm (raw logits)
        {
            const unsigned short* Bb2 = WpT + (size_t)(g * KC + 16 * wv + lm) * 256 + (q << 3);
            short8 b2[2];
            b2[0] = *reinterpret_cast<const short8*>(Bb2);
            floatx4 acc2[4];
#pragma unroll
            for (int mi = 0; mi < 4; mi++) acc2[mi] = (floatx4)0.f;
#pragma unroll
            for (int k = 0; k < 8; k++) {
                if (k < 7) b2[(k + 1) & 1] = *reinterpret_cast<const short8*>(Bb2 + ((k + 1) << 5));
                short8 aF[4];
                int swz = (4 * k + q) ^ (lm & 7);
#pragma unroll
                for (int mi = 0; mi < 4; mi++)
                    aF[mi] = *reinterpret_cast<const short8*>(&sm.pool.lA[((16 * mi + lm) * 32 + swz) * 8]);
#pragma unroll
                for (int mi = 0; mi < 4; mi++)
                    acc2[mi] = __builtin_amdgcn_mfma_f32_16x16x32_bf16(aF[mi], b2[k & 1], acc2[mi], 0, 0, 0);
            }
            float bv = bp[g * KC + 16 * wv + lm];
#pragma unroll
            for (int mi = 0; mi < 4; mi++)
#pragma unroll
                for (int r = 0; r < 4; r++)
                    sm.pool.raw[(16 * mi + 4 * q + r) * 68 + 16 * wv + lm] = acc2[mi][r] + bv;
        }
        __syncthreads();
        if (tid < 64)
            sm.pool.rn[tid] = 1.0f / fmaxf(sqrtf(sm.pool.ssq[tid] + sm.pool.ssq[64 + tid] +
                                           sm.pool.ssq[128 + tid] + sm.pool.ssq[192 + tid] + cF[0]), 1e-12f);
        __syncthreads();
        {
            int row = tid >> 2, j = tid & 3;
            int nloc = ((bx & 7) << 6) + row;
            float rn = sm.pool.rn[row];
            float v[16];
            float mx = -1e30f;
#pragma unroll
            for (int c4 = 0; c4 < 4; c4++) {
                float4 rv = *reinterpret_cast<const float4*>(&sm.pool.raw[row * 68 + 16 * j + 4 * c4]);
                v[4 * c4 + 0] = fmaxf(rv.x * rn, 0.f);
                v[4 * c4 + 1] = fmaxf(rv.y * rn, 0.f);
                v[4 * c4 + 2] = fmaxf(rv.z * rn, 0.f);
                v[4 * c4 + 3] = fmaxf(rv.w * rn, 0.f);
            }
#pragma unroll
            for (int c = 0; c < 16; c++) mx = fmaxf(mx, v[c]);
            mx = fmaxf(mx, __shfl_xor(mx, 1, 64));
            mx = fmaxf(mx, __shfl_xor(mx, 2, 64));
            float z = 0.f;
#pragma unroll
            for (int c = 0; c < 16; c++) { v[c] = __expf(v[c] - mx); z += v[c]; }
            z += __shfl_xor(z, 1, 64);
            z += __shfl_xor(z, 2, 64);
            float iz = 1.0f / z;
#pragma unroll
            for (int c4 = 0; c4 < 4; c4++) {
                size_t tb = (size_t)(g * KC + 16 * j + 4 * c4) * NPER + nloc;
                sT[tb] = f2b(v[4 * c4 + 0] * iz);
                sT[tb + NPER] = f2b(v[4 * c4 + 1] * iz);
                sT[tb + 2 * NPER] = f2b(v[4 * c4 + 2] * iz);
                sT[tb + 3 * NPER] = f2b(v[4 * c4 + 3] * iz);
            }
        }
    }
}

// ---- a_s via MFMA: asT[cl][dst] = sum_src sT[cl][src] * A[dst][src] ----
__global__ __launch_bounds__(256) void as_mfma_kernel(
    const unsigned short* __restrict__ sT, const unsigned short* __restrict__ Aadj,
    unsigned short* __restrict__ asT) {
    __shared__ alignas(16) unsigned short lS[64 * 512];
    int tid = threadIdx.x, bx = blockIdx.x;
    int g = bx >> 1, half = bx & 1;
    int wv = tid >> 6, lane = tid & 63, q = lane >> 4, lm = lane & 15;
#pragma unroll
    for (int j = 0; j < 16; j++) {
        int u = tid + 256 * j;
        int row = u >> 6, cu = (u & 63) ^ (row & 7);
        gload16(sT + (size_t)(g * KC + row) * NPER + cu * 8, &lS[u * 8]);
    }
    floatx4 acc[4][4];
#pragma unroll
    for (int mi = 0; mi < 4; mi++)
#pragma unroll
        for (int nt = 0; nt < 4; nt++) acc[mi][nt] = (floatx4)0.f;
    __syncthreads();
    int dbase = half * 256 + wv * 64;
    const unsigned short* Bb = Aadj + (size_t)(g * 512 + dbase + lm) * 512 + (q << 3);
    short8 bF[2][4];
#pragma unroll
    for (int nt = 0; nt < 4; nt++)
        bF[0][nt] = *reinterpret_cast<const short8*>(Bb + (size_t)16 * nt * 512);
    for (int ki = 0; ki < 16; ki++) {
        if (ki < 15) {
#pragma unroll
            for (int nt = 0; nt < 4; nt++)
                bF[(ki + 1) & 1][nt] =
                    *reinterpret_cast<const short8*>(Bb + (size_t)16 * nt * 512 + (ki + 1) * 32);
        }
        short8 aF[4];
        int swz = (4 * ki + q) ^ (lm & 7);
#pragma unroll
        for (int mi = 0; mi < 4; mi++)
            aF[mi] = *reinterpret_cast<const short8*>(&lS[((16 * mi + lm) * 64 + swz) * 8]);
#pragma unroll
        for (int mi = 0; mi < 4; mi++)
#pragma unroll
            for (int nt = 0; nt < 4; nt++)
                acc[mi][nt] = __builtin_amdgcn_mfma_f32_16x16x32_bf16(aF[mi], bF[ki & 1][nt],
                                                                      acc[mi][nt], 0, 0, 0);
    }
#pragma unroll
    for (int mi = 0; mi < 4; mi++)
#pragma unroll
        for (int r = 0; r < 4; r++) {
            int row = 16 * mi + 4 * q + r;
#pragma unroll
            for (int nt = 0; nt < 4; nt++)
                asT[(size_t)(g * KC + row) * NPER + dbase + 16 * nt + lm] = f2b(acc[mi][nt][r]);
        }
}

// ---- hnew+adj: blocks 0-31 compute graph g (plain stores); 32-255 zero off-diag adj ----
__global__ __launch_bounds__(256) void hnew_adj2_kernel(
    const unsigned short* __restrict__ sT, const unsigned short* __restrict__ featT,
    const unsigned short* __restrict__ asT, float* __restrict__ adjf,
    float* __restrict__ hnewf) {
    __shared__ alignas(16) unsigned short lS[1024 * 8];
    __shared__ alignas(16) unsigned short lF[2048 * 8];
    __shared__ alignas(16) unsigned short lAS[1024 * 8];
    int tid = threadIdx.x, b = blockIdx.x;
    if (b >= 32) {
        uint4 z = { 0u, 0u, 0u, 0u };
        for (int row = b - 32; row < AS; row += 224) {
            int g = row >> 6;
            uint4* out = reinterpret_cast<uint4*>(adjf + (size_t)row * AS);
            for (int i = tid; i < 512; i += 256)
                if (i < g * 16 || i >= g * 16 + 16) out[i] = z;
        }
        return;
    }
    int g = b;
    int wv = tid >> 6, lane = tid & 63, q = lane >> 4, lm = lane & 15;
    bool isH = (wv < 2);
    floatx4 accH[4][4];
    floatx4 accA[4][2];
#pragma unroll
    for (int mi = 0; mi < 4; mi++) {
#pragma unroll
        for (int ni = 0; ni < 4; ni++) accH[mi][ni] = (floatx4)0.f;
#pragma unroll
        for (int ni = 0; ni < 2; ni++) accA[mi][ni] = (floatx4)0.f;
    }
    for (int ks = 0; ks < 4; ks++) {
#pragma unroll
        for (int j = 0; j < 4; j++) {
            int u = tid + 256 * j;
            int row = u >> 4, cu = (u & 15) ^ (row & 15);
            gload16(sT + (size_t)(g * KC + row) * NPER + ks * 128 + cu * 8, &lS[u * 8]);
        }
#pragma unroll
        for (int j = 0; j < 8; j++) {
            int u = tid + 256 * j;
            int row = u >> 4, cu = (u & 15) ^ (row & 15);
            gload16(featT + (size_t)row * NN + g * NPER + ks * 128 + cu * 8, &lF[u * 8]);
        }
#pragma unroll
        for (int j = 0; j < 4; j++) {
            int u = tid + 256 * j;
            int row = u >> 4, cu = (u & 15) ^ (row & 15);
            gload16(asT + (size_t)(g * KC + row) * NPER + ks * 128 + cu * 8, &lAS[u * 8]);
        }
        __syncthreads();
#pragma unroll
        for (int kk = 0; kk < 4; kk++) {
            short8 aF[4];
#pragma unroll
            for (int mi = 0; mi < 4; mi++)
                aF[mi] = *reinterpret_cast<const short8*>(
                    &lS[((16 * mi + lm) * 16 + ((4 * kk + q) ^ lm)) * 8]);
            if (isH) {
                short8 bF[4];
#pragma unroll
                for (int ni = 0; ni < 4; ni++)
                    bF[ni] = *reinterpret_cast<const short8*>(
                        &lF[((64 * wv + 16 * ni + lm) * 16 + ((4 * kk + q) ^ lm)) * 8]);
#pragma unroll
                for (int mi = 0; mi < 4; mi++)
#pragma unroll
                    for (int ni = 0; ni < 4; ni++)
                        accH[mi][ni] = __builtin_amdgcn_mfma_f32_16x16x32_bf16(aF[mi], bF[ni],
                                                                               accH[mi][ni], 0, 0, 0);
            } else {
                short8 bF[2];
#pragma unroll
                for (int ni = 0; ni < 2; ni++)
                    bF[ni] = *reinterpret_cast<const short8*>(
                        &lAS[((32 * (wv - 2) + 16 * ni + lm) * 16 + ((4 * kk + q) ^ lm)) * 8]);
#pragma unroll
                for (int mi = 0; mi < 4; mi++)
#pragma unroll
                    for (int ni = 0; ni < 2; ni++)
                        accA[mi][ni] = __builtin_amdgcn_mfma_f32_16x16x32_bf16(aF[mi], bF[ni],
                                                                               accA[mi][ni], 0, 0, 0);
            }
        }
        __syncthreads();
    }
    if (isH) {
#pragma unroll
        for (int mi = 0; mi < 4; mi++)
#pragma unroll
            for (int ni = 0; ni < 4; ni++)
#pragma unroll
                for (int r = 0; r < 4; r++)
                    hnewf[(size_t)(g * KC + 16 * mi + 4 * q + r) * DD +
                          64 * wv + 16 * ni + lm] = accH[mi][ni][r];
    } else {
#pragma unroll
        for (int mi = 0; mi < 4; mi++)
#pragma unroll
            for (int ni = 0; ni < 2; ni++)
#pragma unroll
                for (int r = 0; r < 4; r++)
                    adjf[(size_t)(g * KC + 16 * mi + 4 * q + r) * AS +
                         g * KC + 32 * (wv - 2) + 16 * ni + lm] = accA[mi][ni][r];
    }
}

extern "C" void kernel_launch(void* const* d_in, const int* in_sizes, int n_in,
                              void* d_out, int out_size, void* d_ws, size_t ws_size,
                              hipStream_t stream) {
    const float* h   = (const float*)d_in[0];
    const float* Wf  = (const float*)d_in[1];
    const float* bfe = (const float*)d_in[2];
    const float* Wp  = (const float*)d_in[3];
    const float* bp  = (const float*)d_in[4];
    const int* esrc  = (const int*)d_in[5];
    const int* edst  = (const int*)d_in[6];

    float* adjf  = (float*)d_out;
    float* hnewf = adjf + (size_t)AS * AS;

    unsigned short* bundle = (unsigned short*)d_ws;        // NN*256 bf16
    unsigned short* WfT   = bundle + (size_t)NN * 256;     // 128*256
    unsigned short* WpT   = WfT + 128 * 256;               // 2048*256
    unsigned short* sT    = WpT + (size_t)AS * 256;        // NN*KC
    unsigned short* asT   = sT + (size_t)NN * KC;          // NN*KC
    unsigned short* featT = asT + (size_t)NN * KC;         // DD*NN
    unsigned short* hT    = featT + (size_t)DD * NN;       // DD*NN
    unsigned short* Aadj  = hT + (size_t)DD * NN;          // NN*512 bf16 (16 MB)
    float* invdeg = (float*)(Aadj + (size_t)NN * 512);     // NN
    unsigned int* Acnt = (unsigned int*)(invdeg + NN);     // NN*512 bytes (8.4 MB)
    float* Gf = (float*)(Acnt + (size_t)NN * 128);         // 256*256 fp32
    float* uF = Gf + 65536;                                // 256 fp32
    float* cF = uF + 256;                                  // 1 fp32 (+pad)
    unsigned short* Wpb = (unsigned short*)(cF + 4);       // 256*2048 bf16
    unsigned short* Gb  = Wpb + (size_t)256 * 2048;        // 256*256 bf16

    // zero Acnt + Gf + uF + cF in one shot (contiguous)
    hipMemsetAsync(Acnt, 0, (size_t)NN * 512 + (65536 + 256 + 4) * sizeof(float), stream);

    prep_kernel<<<2208, 256, 0, stream>>>(h, bundle, hT, esrc, edst, Acnt, Wf, Wp, WfT, WpT, Wpb);
    conv_kernel<<<2064, 256, 0, stream>>>(Acnt, Aadj, invdeg, Wpb, Wp, bp, Gf, uF, cF);
    agg_h_mfma_kernel<<<260, 256, 0, stream>>>(Aadj, hT, invdeg, bundle, Gf, Gb);
    featpool_kernel<<<384, 256, 0, stream>>>(bundle, WfT, WpT, Gb, bfe, bp, uF, cF, featT, sT);
    as_mfma_kernel<<<NB * 2, 256, 0, stream>>>(sT, Aadj, asT);
    hnew_adj2_kernel<<<256, 256, 0, stream>>>(sT, featT, asT, adjf, hnewf);
}